// Round 4
// baseline (4479.599 us; speedup 1.0000x reference)
//
#include <hip/hip_runtime.h>
#include <math.h>

// Problem dims
#define BB 32
#define NN 32
#define EE 256
#define HH 1500
#define G4 6000      // 4*HH
#define QIN 512
#define Q1O 600
#define QO 300
#define EV1 1000
#define EV2 100
#define EV3 10
#define PP 496       // N*(N-1)/2
#define ROWS (BB*PP) // 15872
#define BH (BB*HH)   // 48000

// persistent LSTM config
#define NBLK 250     // blocks (<=256 CUs, all resident)
#define JHB 6        // hidden units per block (250*6 = 1500)
#define ROWSB 24     // 4 gates * JHB
#define CK 768       // k-chunk staged in LDS (2 chunks cover 1500, pad to 1536)
#define HPAD 17      // LDS row stride (k-row of 16 b + 1 pad; gcd(17,32)=1)

__device__ __forceinline__ float sigm(float x) { return 1.f / (1.f + expf(-x)); }

// ---------------- init helpers ----------------
__global__ void k_zero(float* a, int n) {
    int i = blockIdx.x * 256 + threadIdx.x;
    if (i < n) a[i] = 0.f;
}

__global__ void k_iijj(int* iijj) {
    int p = threadIdx.x;
    if (p >= PP) return;
    int i = 0, p0 = 0;
    while (p >= p0 + (NN - 1 - i)) { p0 += NN - 1 - i; i++; }
    iijj[p] = i;
    iijj[PP + p] = i + 1 + (p - p0);
}

// q1 effective bias: q1_b[o] + sum over odd k of q1_w[o][k]  (PE at pos 0)
__global__ void k_q1beff(const float* q1w, const float* q1b, float* beff) {
    int o = blockIdx.x * 256 + threadIdx.x;
    if (o >= Q1O) return;
    float a = q1b[o];
    for (int k = 1; k < QIN; k += 2) a += q1w[o * QIN + k];
    beff[o] = a;
}

__global__ void k_addb(const float* a, const float* b, float* c, int n) {
    int i = blockIdx.x * 256 + threadIdx.x;
    if (i < n) c[i] = a[i] + b[i];
}

// ---------------- transpose (sub-range of columns) ----------------
__global__ void k_transpose(const float* __restrict__ src, float* __restrict__ dst,
                            int R, int C, int c0, int csub) {
    __shared__ float tile[32][33];
    int cb = blockIdx.x * 32, rb = blockIdx.y * 32;
    for (int dy = threadIdx.y; dy < 32; dy += 8) {
        int r = rb + dy, c = cb + threadIdx.x;
        if (r < R && c < csub) tile[dy][threadIdx.x] = src[(size_t)r * C + c0 + c];
    }
    __syncthreads();
    for (int dy = threadIdx.y; dy < 32; dy += 8) {
        int c = cb + dy, r = rb + threadIdx.x;
        if (c < csub && r < R) dst[(size_t)c * R + r] = tile[threadIdx.x][dy];
    }
}

// ---------------- sort along parts axis ----------------
__global__ void k_sort(const float* __restrict__ x, float* __restrict__ seq) {
    int tid = blockIdx.x * 256 + threadIdx.x;
    if (tid >= BB * EE) return;
    int b = tid / EE, e = tid % EE;
    float v[NN];
    for (int n = 0; n < NN; n++) v[n] = x[(b * NN + n) * EE + e];
    for (int i = 1; i < NN; i++) {
        float key = v[i];
        int j = i - 1;
        while (j >= 0 && v[j] > key) { v[j + 1] = v[j]; j--; }
        v[j + 1] = key;
    }
    for (int n = 0; n < NN; n++) seq[(n * BB + b) * EE + e] = v[n];
}

// ---------------- transpose xg[(n*32+b)][j] -> xgT[n][j][b] ----------------
__global__ void k_xgt(const float* __restrict__ xg, float* __restrict__ xgT) {
    __shared__ float t[32][33];
    int n = blockIdx.z;
    int j0 = blockIdx.x * 32;
    for (int dy = threadIdx.y; dy < 32; dy += 8) {
        int j = j0 + threadIdx.x;
        if (j < G4) t[dy][threadIdx.x] = xg[(size_t)(n * 32 + dy) * G4 + j];
    }
    __syncthreads();
    for (int dy = threadIdx.y; dy < 32; dy += 8) {
        int j = j0 + dy;
        if (j < G4) xgT[(size_t)n * (G4 * BB) + (size_t)j * BB + threadIdx.x] = t[threadIdx.x][dy];
    }
}

// ---------------- pairs gather ----------------
__global__ void k_pairs(const float* __restrict__ x, const int* __restrict__ iijj,
                        float* __restrict__ pairs) {
    int idx = blockIdx.x * 256 + threadIdx.x; // quad index
    int r = idx >> 7;
    if (r >= ROWS) return;
    int q = idx & 127, k = q << 2;
    int b = r / PP, p = r - b * PP;
    int part = (k < EE) ? iijj[p] : iijj[PP + p];
    float4 v = *(const float4*)(x + (size_t)(b * NN + part) * EE + (k & (EE - 1)));
    *(float4*)(pairs + (size_t)r * QIN + k) = v;
}

// ---------------- tiled GEMM: C[M][N] = act(A[M][K] @ Bw[K][N] + bias + pb) ----------------
__global__ void k_gemm(const float* __restrict__ A, const float* __restrict__ Bw,
                       const float* __restrict__ bias, const float* __restrict__ pbm,
                       float* __restrict__ C, int M, int K, int N, int relu) {
    __shared__ __align__(16) float As[16][68];
    __shared__ __align__(16) float Bs[16][64];
    int tid = threadIdx.x;
    int m0 = blockIdx.y * 64, n0 = blockIdx.x * 64;
    int am = tid >> 2, ak4 = (tid & 3) << 2;
    int bk = tid >> 4, bn4 = (tid & 15) << 2;
    int tm = tid >> 4, tn = tid & 15;
    float acc[4][4] = {{0.f}};
    for (int k0 = 0; k0 < K; k0 += 16) {
        float4 av = {0.f, 0.f, 0.f, 0.f};
        if (k0 + ak4 < K) av = *(const float4*)(A + (size_t)(m0 + am) * K + k0 + ak4);
        float4 bv = {0.f, 0.f, 0.f, 0.f};
        if (k0 + bk < K && n0 + bn4 < N) bv = *(const float4*)(Bw + (size_t)(k0 + bk) * N + n0 + bn4);
        __syncthreads();
        As[ak4 + 0][am] = av.x; As[ak4 + 1][am] = av.y;
        As[ak4 + 2][am] = av.z; As[ak4 + 3][am] = av.w;
        *(float4*)&Bs[bk][bn4] = bv;
        __syncthreads();
#pragma unroll
        for (int kk = 0; kk < 16; kk++) {
            float4 a = *(const float4*)&As[kk][tm << 2];
            float4 b = *(const float4*)&Bs[kk][tn << 2];
            acc[0][0] += a.x * b.x; acc[0][1] += a.x * b.y; acc[0][2] += a.x * b.z; acc[0][3] += a.x * b.w;
            acc[1][0] += a.y * b.x; acc[1][1] += a.y * b.y; acc[1][2] += a.y * b.z; acc[1][3] += a.y * b.w;
            acc[2][0] += a.z * b.x; acc[2][1] += a.z * b.y; acc[2][2] += a.z * b.z; acc[2][3] += a.z * b.w;
            acc[3][0] += a.w * b.x; acc[3][1] += a.w * b.y; acc[3][2] += a.w * b.z; acc[3][3] += a.w * b.w;
        }
    }
    int col0 = n0 + (tn << 2);
    if (col0 >= N) return;
    float4 bb0 = {0.f, 0.f, 0.f, 0.f};
    if (bias) bb0 = *(const float4*)(bias + col0);
#pragma unroll
    for (int i = 0; i < 4; i++) {
        int row = m0 + (tm << 2) + i;
        float4 pv = {0.f, 0.f, 0.f, 0.f};
        if (pbm) pv = *(const float4*)(pbm + (size_t)(row / PP) * N + col0);
        float4 r;
        r.x = acc[i][0] + bb0.x + pv.x;
        r.y = acc[i][1] + bb0.y + pv.y;
        r.z = acc[i][2] + bb0.z + pv.z;
        r.w = acc[i][3] + bb0.w + pv.w;
        if (relu) {
            r.x = fmaxf(r.x, 0.f); r.y = fmaxf(r.y, 0.f);
            r.z = fmaxf(r.z, 0.f); r.w = fmaxf(r.w, 0.f);
        }
        *(float4*)(C + (size_t)row * N + col0) = r;
    }
}

// ---------------- persistent LSTM: all 32 steps in one kernel ----------------
// 250 blocks x 512 threads, all resident. Each block owns 6 hidden units
// (24 gate rows). Each thread holds 72 w_hh weights in VGPRs (loaded once,
// coalesced: consecutive lanes -> consecutive k). h ping-pong global buffer
// ht[pp][bh][k][16]; staged per (bh, chunk) into LDS (pad 17 -> 2-way-free).
// One device-scope barrier per step (monotonic atomic counter).
__global__ __launch_bounds__(512, 2)
void k_lstm_persist(const float* __restrict__ whh, const float* __restrict__ xgT,
                    float* __restrict__ ht, int* __restrict__ bar) {
    __shared__ float hs[CK * HPAD];      // 52224 B
    __shared__ float red[ROWSB * 16];    // 1536 B
    __shared__ float cs[JHB * 32];       // 768 B
    const int tid = threadIdx.x;
    const int bid = blockIdx.x;
    const int w = tid >> 6;   // wave index = row-group (3 rows)
    const int l = tid & 63;   // lane = k interleave offset
    const int jh0 = bid * JHB;

    // load weights into VGPRs: wreg[i][c][t] = w_hh[j][c*768 + 64*t + l]
    float wreg[3][2][12];
#pragma unroll
    for (int i = 0; i < 3; i++) {
        int r = w * 3 + i;
        int j = (r / JHB) * HH + jh0 + (r % JHB);
        const float* wr = whh + (size_t)j * HH;
#pragma unroll
        for (int c = 0; c < 2; c++)
#pragma unroll
            for (int t = 0; t < 12; t++) {
                int k = c * CK + (t << 6) + l;
                wreg[i][c][t] = (k < HH) ? wr[k] : 0.f;
            }
    }
    if (tid < JHB * 32) cs[tid] = 0.f;
    __syncthreads();

    for (int n = 0; n < NN; n++) {
        const int pp = n & 1, np = (n + 1) & 1;
#pragma unroll 1
        for (int bh = 0; bh < 2; bh++) {
            float acc[3][16];
#pragma unroll
            for (int i = 0; i < 3; i++)
#pragma unroll
                for (int b = 0; b < 16; b++) acc[i][b] = 0.f;
#pragma unroll 1
            for (int c = 0; c < 2; c++) {
                __syncthreads();  // hs reuse safe
                const float* hsrc = ht + ((size_t)(pp * 2 + bh) * HH) * 16;
                for (int idx = tid; idx < CK * 16; idx += 512) {
                    int kk = idx >> 4, b = idx & 15;
                    int k = c * CK + kk;
                    hs[kk * HPAD + b] = (k < HH) ? hsrc[(size_t)k * 16 + b] : 0.f;
                }
                __syncthreads();
#pragma unroll
                for (int t = 0; t < 12; t++) {
                    const float* hrow = &hs[((t << 6) + l) * HPAD];
                    float hv[16];
#pragma unroll
                    for (int b = 0; b < 16; b++) hv[b] = hrow[b];
#pragma unroll
                    for (int i = 0; i < 3; i++) {
                        float wv = wreg[i][c][t];
#pragma unroll
                        for (int b = 0; b < 16; b++) acc[i][b] += wv * hv[b];
                    }
                }
            }
            // butterfly reduce over the 64-lane k-split
#pragma unroll
            for (int off = 32; off >= 1; off >>= 1)
#pragma unroll
                for (int i = 0; i < 3; i++)
#pragma unroll
                    for (int b = 0; b < 16; b++)
                        acc[i][b] += __shfl_xor(acc[i][b], off);
            if (l == 0) {
#pragma unroll
                for (int i = 0; i < 3; i++)
#pragma unroll
                    for (int b = 0; b < 16; b++)
                        red[(w * 3 + i) * 16 + b] = acc[i][b];
            }
            __syncthreads();
            // gate nonlinearity for this b-half
            if (tid < JHB * 16) {
                int u = tid >> 4, bcol = tid & 15;
                int jb = jh0 + u;
                float g4[4];
#pragma unroll
                for (int g = 0; g < 4; g++)
                    g4[g] = red[(g * JHB + u) * 16 + bcol]
                          + xgT[((size_t)n * G4 + (size_t)g * HH + jb) * BB + bh * 16 + bcol];
                float ci = cs[u * 32 + bh * 16 + bcol];
                float cn = sigm(g4[1]) * ci + sigm(g4[0]) * tanhf(g4[2]);
                cs[u * 32 + bh * 16 + bcol] = cn;
                ht[((size_t)(np * 2 + bh) * HH + jb) * 16 + bcol] = sigm(g4[3]) * tanhf(cn);
            }
        }
        // grid barrier (monotonic counter; device-scope fences)
        __syncthreads();
        __threadfence();
        if (tid == 0) {
            atomicAdd(bar, 1);
            int target = NBLK * (n + 1);
            while (atomicAdd(bar, 0) < target) __builtin_amdgcn_s_sleep(16);
        }
        __syncthreads();
        __threadfence();
    }
}

// ---------------- plan-side e1 bias (plan in ht[0][bh][k][16] layout) ----------------
__global__ void k_pb(const float* __restrict__ ht, const float* __restrict__ e1at,
                     const float* __restrict__ e1b, float* __restrict__ pb) {
    __shared__ float ps[HH];
    int b = blockIdx.y;
    int bh = b >> 4, bc = b & 15;
    for (int idx = threadIdx.x; idx < HH; idx += 256)
        ps[idx] = ht[((size_t)bh * HH + idx) * 16 + bc];
    __syncthreads();
    int o = blockIdx.x * 256 + threadIdx.x;
    if (o >= EV1) return;
    float acc = e1b[o];
    for (int k = 0; k < HH; k++) acc += ps[k] * e1at[(size_t)k * EV1 + o];
    pb[b * EV1 + o] = acc;
}

// ---------------- fused e3 + e4 tail ----------------
__global__ void k_e34(const float* __restrict__ e2out, const float* __restrict__ e3t,
                      const float* __restrict__ e3b, const float* __restrict__ e4w,
                      const float* __restrict__ e4b, float* __restrict__ out) {
    __shared__ float wt[EV2 * EV3];
    for (int idx = threadIdx.x; idx < EV2 * EV3; idx += 256) wt[idx] = e3t[idx];
    __syncthreads();
    int r = blockIdx.x * 256 + threadIdx.x;
    if (r >= ROWS) return;
    float h3[EV3];
#pragma unroll
    for (int o3 = 0; o3 < EV3; o3++) h3[o3] = e3b[o3];
    for (int k = 0; k < EV2; k++) {
        float v = e2out[(size_t)r * EV2 + k];
#pragma unroll
        for (int o3 = 0; o3 < EV3; o3++) h3[o3] += v * wt[k * EV3 + o3];
    }
    float acc = e4b[0];
#pragma unroll
    for (int o3 = 0; o3 < EV3; o3++) acc += fmaxf(h3[o3], 0.f) * e4w[o3];
    out[r] = fmaxf(acc, 0.f);
}

// ---------------- host launch ----------------
extern "C" void kernel_launch(void* const* d_in, const int* in_sizes, int n_in,
                              void* d_out, int out_size, void* d_ws, size_t ws_size,
                              hipStream_t stream) {
    const float* x    = (const float*)d_in[0];
    const float* w_ih = (const float*)d_in[1];
    const float* w_hh = (const float*)d_in[2];
    const float* b_ih = (const float*)d_in[3];
    const float* b_hh = (const float*)d_in[4];
    const float* q1_w = (const float*)d_in[5];
    const float* q1_b = (const float*)d_in[6];
    const float* q2_w = (const float*)d_in[7];
    const float* q2_b = (const float*)d_in[8];
    const float* e1_w = (const float*)d_in[9];
    const float* e1_b = (const float*)d_in[10];
    const float* e2_w = (const float*)d_in[11];
    const float* e2_b = (const float*)d_in[12];
    const float* e3_w = (const float*)d_in[13];
    const float* e3_b = (const float*)d_in[14];
    const float* e4_w = (const float*)d_in[15];
    const float* e4_b = (const float*)d_in[16];
    float* out = (float*)d_out;
    float* ws = (float*)d_ws;

    // workspace layout (float offsets)
    size_t off = 0;
    float* seq    = ws + off; off += (size_t)NN * BB * EE;          // 262,144
    size_t regionA = off; off += 17700000;
    // regionA phases:
    //  pre-LSTM : xg [0, 6.15M)
    //  pairs/q1 : pairs [0,8.13M) | q1out [8.13M,17.66M)   (xg dead after xgT)
    //  e1       : e1out [0,15.87M)                          (pairs,q1out dead)
    float* xg     = ws + regionA;                                   // 6,144,000
    float* pairs  = ws + regionA;                                   // 8,126,464
    float* q1out  = ws + regionA + 8130000;                         // 9,523,200
    float* e1out  = ws + regionA;                                   // 15,872,000
    float* xgT    = ws + off; off += (size_t)NN * G4 * BB;          // 6,144,000
    float* ht     = ws + off; off += 2 * 2 * HH * 16;               // 96,000 (ping-pong, b-halved)
    float* wih_t  = ws + off; off += (size_t)EE * G4;               // 1,536,000
    float* q1t    = ws + off; off += (size_t)QIN * Q1O;
    float* q1beff = ws + off; off += 1024;
    float* bsum   = ws + off; off += G4;
    float* q2t    = ws + off; off += (size_t)Q1O * QO;
    float* e1at   = ws + off; off += (size_t)HH * EV1;
    float* e1bt   = ws + off; off += (size_t)QO * EV1;
    float* e2t    = ws + off; off += (size_t)EV1 * EV2;
    float* e3t    = ws + off; off += 1024;
    float* pb     = ws + off; off += BB * EV1;
    float* q2out  = ws + off; off += (size_t)ROWS * QO;
    float* e2out  = ws + off; off += (size_t)ROWS * EV2;
    int*   iijj   = (int*)(ws + off); off += 1024;
    int*   bar    = (int*)(ws + off); off += 256;

    dim3 tb(32, 8);

    // init
    k_iijj<<<1, 512, 0, stream>>>(iijj);
    k_q1beff<<<3, 256, 0, stream>>>(q1_w, q1_b, q1beff);
    k_addb<<<24, 256, 0, stream>>>(b_ih, b_hh, bsum, G4);
    k_zero<<<376, 256, 0, stream>>>(ht, 2 * 2 * HH * 16);
    k_zero<<<1, 256, 0, stream>>>((float*)bar, 64);

    // weight transforms
    k_transpose<<<dim3(8, 188), tb, 0, stream>>>(w_ih, wih_t, G4, EE, 0, EE);
    k_transpose<<<dim3(16, 19), tb, 0, stream>>>(q1_w, q1t, Q1O, QIN, 0, QIN);
    k_transpose<<<dim3(19, 10), tb, 0, stream>>>(q2_w, q2t, QO, Q1O, 0, Q1O);
    k_transpose<<<dim3(47, 32), tb, 0, stream>>>(e1_w, e1at, EV1, HH + QO, 0, HH);
    k_transpose<<<dim3(10, 32), tb, 0, stream>>>(e1_w, e1bt, EV1, HH + QO, HH, QO);
    k_transpose<<<dim3(32, 4), tb, 0, stream>>>(e2_w, e2t, EV2, EV1, 0, EV1);
    k_transpose<<<dim3(4, 1), tb, 0, stream>>>(e3_w, e3t, EV3, EV2, 0, EV2);

    // sort + x-side gates (xg = seq @ wih_t + bsum), then transpose to [n][j][b]
    k_sort<<<32, 256, 0, stream>>>(x, seq);
    k_gemm<<<dim3(94, 16), 256, 0, stream>>>(seq, wih_t, bsum, nullptr, xg, 1024, EE, G4, 0);
    k_xgt<<<dim3(188, 1, 32), tb, 0, stream>>>(xg, xgT);

    // LSTM: single persistent kernel, 32 steps with internal grid barrier
    k_lstm_persist<<<NBLK, 512, 0, stream>>>(w_hh, xgT, ht, bar);

    // evaluator plan-side bias (plan = ht buffer 0 after 32 steps)
    k_pb<<<dim3(4, BB), 256, 0, stream>>>(ht, e1at, e1_b, pb);

    // pair MLP
    k_pairs<<<7936, 256, 0, stream>>>(x, iijj, pairs);
    k_gemm<<<dim3(10, 248), 256, 0, stream>>>(pairs, q1t, q1beff, nullptr, q1out, ROWS, QIN, Q1O, 1);
    k_gemm<<<dim3(5, 248), 256, 0, stream>>>(q1out, q2t, q2_b, nullptr, q2out, ROWS, Q1O, QO, 1);
    k_gemm<<<dim3(16, 248), 256, 0, stream>>>(q2out, e1bt, nullptr, pb, e1out, ROWS, QO, EV1, 1);
    k_gemm<<<dim3(2, 248), 256, 0, stream>>>(e1out, e2t, e2_b, nullptr, e2out, ROWS, EV1, EV2, 1);
    k_e34<<<62, 256, 0, stream>>>(e2out, e3t, e3_b, e4_w, e4_b, out);
}

// Round 5
// 4473.432 us; speedup vs baseline: 1.0014x; 1.0014x over previous
//
#include <hip/hip_runtime.h>
#include <math.h>

// Problem dims
#define BB 32
#define NN 32
#define EE 256
#define HH 1500
#define G4 6000      // 4*HH
#define QIN 512
#define Q1O 600
#define QO 300
#define EV1 1000
#define EV2 100
#define EV3 10
#define PP 496       // N*(N-1)/2
#define ROWS (BB*PP) // 15872
#define BH (BB*HH)   // 48000

// persistent LSTM config
#define NBLK 250     // blocks (<=256 CUs, all resident)
#define JHB 6        // hidden units per block (250*6 = 1500)
#define ROWSB 24     // 4 gates * JHB
#define CK 768       // k-chunk staged in LDS (2 chunks cover 1500, pad to 1536)
#define HPAD 17      // LDS row stride (k-row of 16 b + 1 pad; gcd(17,32)=1)

__device__ __forceinline__ float sigm(float x) { return 1.f / (1.f + expf(-x)); }

// ---------------- init helpers ----------------
__global__ void k_zero(float* a, int n) {
    int i = blockIdx.x * 256 + threadIdx.x;
    if (i < n) a[i] = 0.f;
}

__global__ void k_iijj(int* iijj) {
    int p = threadIdx.x;
    if (p >= PP) return;
    int i = 0, p0 = 0;
    while (p >= p0 + (NN - 1 - i)) { p0 += NN - 1 - i; i++; }
    iijj[p] = i;
    iijj[PP + p] = i + 1 + (p - p0);
}

// q1 effective bias: q1_b[o] + sum over odd k of q1_w[o][k]  (PE at pos 0)
__global__ void k_q1beff(const float* q1w, const float* q1b, float* beff) {
    int o = blockIdx.x * 256 + threadIdx.x;
    if (o >= Q1O) return;
    float a = q1b[o];
    for (int k = 1; k < QIN; k += 2) a += q1w[o * QIN + k];
    beff[o] = a;
}

__global__ void k_addb(const float* a, const float* b, float* c, int n) {
    int i = blockIdx.x * 256 + threadIdx.x;
    if (i < n) c[i] = a[i] + b[i];
}

// ---------------- transpose (sub-range of columns) ----------------
__global__ void k_transpose(const float* __restrict__ src, float* __restrict__ dst,
                            int R, int C, int c0, int csub) {
    __shared__ float tile[32][33];
    int cb = blockIdx.x * 32, rb = blockIdx.y * 32;
    for (int dy = threadIdx.y; dy < 32; dy += 8) {
        int r = rb + dy, c = cb + threadIdx.x;
        if (r < R && c < csub) tile[dy][threadIdx.x] = src[(size_t)r * C + c0 + c];
    }
    __syncthreads();
    for (int dy = threadIdx.y; dy < 32; dy += 8) {
        int c = cb + dy, r = rb + threadIdx.x;
        if (c < csub && r < R) dst[(size_t)c * R + r] = tile[threadIdx.x][dy];
    }
}

// ---------------- sort along parts axis ----------------
__global__ void k_sort(const float* __restrict__ x, float* __restrict__ seq) {
    int tid = blockIdx.x * 256 + threadIdx.x;
    if (tid >= BB * EE) return;
    int b = tid / EE, e = tid % EE;
    float v[NN];
    for (int n = 0; n < NN; n++) v[n] = x[(b * NN + n) * EE + e];
    for (int i = 1; i < NN; i++) {
        float key = v[i];
        int j = i - 1;
        while (j >= 0 && v[j] > key) { v[j + 1] = v[j]; j--; }
        v[j + 1] = key;
    }
    for (int n = 0; n < NN; n++) seq[(n * BB + b) * EE + e] = v[n];
}

// ---------------- transpose xg[(n*32+b)][j] -> xgT[n][j][b] ----------------
__global__ void k_xgt(const float* __restrict__ xg, float* __restrict__ xgT) {
    __shared__ float t[32][33];
    int n = blockIdx.z;
    int j0 = blockIdx.x * 32;
    for (int dy = threadIdx.y; dy < 32; dy += 8) {
        int j = j0 + threadIdx.x;
        if (j < G4) t[dy][threadIdx.x] = xg[(size_t)(n * 32 + dy) * G4 + j];
    }
    __syncthreads();
    for (int dy = threadIdx.y; dy < 32; dy += 8) {
        int j = j0 + dy;
        if (j < G4) xgT[(size_t)n * (G4 * BB) + (size_t)j * BB + threadIdx.x] = t[threadIdx.x][dy];
    }
}

// ---------------- pairs gather ----------------
__global__ void k_pairs(const float* __restrict__ x, const int* __restrict__ iijj,
                        float* __restrict__ pairs) {
    int idx = blockIdx.x * 256 + threadIdx.x; // quad index
    int r = idx >> 7;
    if (r >= ROWS) return;
    int q = idx & 127, k = q << 2;
    int b = r / PP, p = r - b * PP;
    int part = (k < EE) ? iijj[p] : iijj[PP + p];
    float4 v = *(const float4*)(x + (size_t)(b * NN + part) * EE + (k & (EE - 1)));
    *(float4*)(pairs + (size_t)r * QIN + k) = v;
}

// ---------------- tiled GEMM: C[M][N] = act(A[M][K] @ Bw[K][N] + bias + pb) ----------------
__global__ void k_gemm(const float* __restrict__ A, const float* __restrict__ Bw,
                       const float* __restrict__ bias, const float* __restrict__ pbm,
                       float* __restrict__ C, int M, int K, int N, int relu) {
    __shared__ __align__(16) float As[16][68];
    __shared__ __align__(16) float Bs[16][64];
    int tid = threadIdx.x;
    int m0 = blockIdx.y * 64, n0 = blockIdx.x * 64;
    int am = tid >> 2, ak4 = (tid & 3) << 2;
    int bk = tid >> 4, bn4 = (tid & 15) << 2;
    int tm = tid >> 4, tn = tid & 15;
    float acc[4][4] = {{0.f}};
    for (int k0 = 0; k0 < K; k0 += 16) {
        float4 av = {0.f, 0.f, 0.f, 0.f};
        if (k0 + ak4 < K) av = *(const float4*)(A + (size_t)(m0 + am) * K + k0 + ak4);
        float4 bv = {0.f, 0.f, 0.f, 0.f};
        if (k0 + bk < K && n0 + bn4 < N) bv = *(const float4*)(Bw + (size_t)(k0 + bk) * N + n0 + bn4);
        __syncthreads();
        As[ak4 + 0][am] = av.x; As[ak4 + 1][am] = av.y;
        As[ak4 + 2][am] = av.z; As[ak4 + 3][am] = av.w;
        *(float4*)&Bs[bk][bn4] = bv;
        __syncthreads();
#pragma unroll
        for (int kk = 0; kk < 16; kk++) {
            float4 a = *(const float4*)&As[kk][tm << 2];
            float4 b = *(const float4*)&Bs[kk][tn << 2];
            acc[0][0] += a.x * b.x; acc[0][1] += a.x * b.y; acc[0][2] += a.x * b.z; acc[0][3] += a.x * b.w;
            acc[1][0] += a.y * b.x; acc[1][1] += a.y * b.y; acc[1][2] += a.y * b.z; acc[1][3] += a.y * b.w;
            acc[2][0] += a.z * b.x; acc[2][1] += a.z * b.y; acc[2][2] += a.z * b.z; acc[2][3] += a.z * b.w;
            acc[3][0] += a.w * b.x; acc[3][1] += a.w * b.y; acc[3][2] += a.w * b.z; acc[3][3] += a.w * b.w;
        }
    }
    int col0 = n0 + (tn << 2);
    if (col0 >= N) return;
    float4 bb0 = {0.f, 0.f, 0.f, 0.f};
    if (bias) bb0 = *(const float4*)(bias + col0);
#pragma unroll
    for (int i = 0; i < 4; i++) {
        int row = m0 + (tm << 2) + i;
        float4 pv = {0.f, 0.f, 0.f, 0.f};
        if (pbm) pv = *(const float4*)(pbm + (size_t)(row / PP) * N + col0);
        float4 r;
        r.x = acc[i][0] + bb0.x + pv.x;
        r.y = acc[i][1] + bb0.y + pv.y;
        r.z = acc[i][2] + bb0.z + pv.z;
        r.w = acc[i][3] + bb0.w + pv.w;
        if (relu) {
            r.x = fmaxf(r.x, 0.f); r.y = fmaxf(r.y, 0.f);
            r.z = fmaxf(r.z, 0.f); r.w = fmaxf(r.w, 0.f);
        }
        *(float4*)(C + (size_t)row * N + col0) = r;
    }
}

// ---------------- persistent LSTM: all 32 steps in one kernel ----------------
// 250 blocks x 512 threads, all resident (1 block/CU, 8 waves). Each block owns
// 6 hidden units (24 gate rows); each thread holds 72 w_hh weights in VGPRs.
// __launch_bounds__(512) (no min-waves arg) -> 256 VGPR budget: wreg 72 +
// acc 48 + hv 16 + temps fits, NO scratch spill (R4's (512,2) capped at 128
// VGPRs and spilled ~1 GB/dispatch).
__global__ __launch_bounds__(512)
void k_lstm_persist(const float* __restrict__ whh, const float* __restrict__ xgT,
                    float* __restrict__ ht, int* __restrict__ bar) {
    __shared__ float hs[CK * HPAD];      // 52224 B
    __shared__ float red[ROWSB * 16];    // 1536 B
    __shared__ float cs[JHB * 32];       // 768 B
    const int tid = threadIdx.x;
    const int bid = blockIdx.x;
    const int w = tid >> 6;   // wave index = row-group (3 rows)
    const int l = tid & 63;   // lane = k interleave offset
    const int jh0 = bid * JHB;

    // load weights into VGPRs: wreg[i][c][t] = w_hh[j][c*768 + 64*t + l]
    float wreg[3][2][12];
#pragma unroll
    for (int i = 0; i < 3; i++) {
        int r = w * 3 + i;
        int j = (r / JHB) * HH + jh0 + (r % JHB);
        const float* wr = whh + (size_t)j * HH;
#pragma unroll
        for (int c = 0; c < 2; c++)
#pragma unroll
            for (int t = 0; t < 12; t++) {
                int k = c * CK + (t << 6) + l;
                wreg[i][c][t] = (k < HH) ? wr[k] : 0.f;
            }
    }
    if (tid < JHB * 32) cs[tid] = 0.f;
    __syncthreads();

    for (int n = 0; n < NN; n++) {
        const int pp = n & 1, np = (n + 1) & 1;
#pragma unroll 1
        for (int bh = 0; bh < 2; bh++) {
            float acc[3][16];
#pragma unroll
            for (int i = 0; i < 3; i++)
#pragma unroll
                for (int b = 0; b < 16; b++) acc[i][b] = 0.f;
#pragma unroll 1
            for (int c = 0; c < 2; c++) {
                __syncthreads();  // hs reuse safe
                const float* hsrc = ht + ((size_t)(pp * 2 + bh) * HH) * 16;
                for (int idx = tid; idx < CK * 16; idx += 512) {
                    int kk = idx >> 4, b = idx & 15;
                    int k = c * CK + kk;
                    hs[kk * HPAD + b] = (k < HH) ? hsrc[(size_t)k * 16 + b] : 0.f;
                }
                __syncthreads();
#pragma unroll
                for (int t = 0; t < 12; t++) {
                    const float* hrow = &hs[((t << 6) + l) * HPAD];
                    float hv[16];
#pragma unroll
                    for (int b = 0; b < 16; b++) hv[b] = hrow[b];
#pragma unroll
                    for (int i = 0; i < 3; i++) {
                        float wv = wreg[i][c][t];
#pragma unroll
                        for (int b = 0; b < 16; b++) acc[i][b] += wv * hv[b];
                    }
                }
            }
            // butterfly reduce over the 64-lane k-split
#pragma unroll
            for (int off = 32; off >= 1; off >>= 1)
#pragma unroll
                for (int i = 0; i < 3; i++)
#pragma unroll
                    for (int b = 0; b < 16; b++)
                        acc[i][b] += __shfl_xor(acc[i][b], off);
            if (l == 0) {
#pragma unroll
                for (int i = 0; i < 3; i++)
#pragma unroll
                    for (int b = 0; b < 16; b++)
                        red[(w * 3 + i) * 16 + b] = acc[i][b];
            }
            __syncthreads();
            // gate nonlinearity for this b-half
            if (tid < JHB * 16) {
                int u = tid >> 4, bcol = tid & 15;
                int jb = jh0 + u;
                float g4[4];
#pragma unroll
                for (int g = 0; g < 4; g++)
                    g4[g] = red[(g * JHB + u) * 16 + bcol]
                          + xgT[((size_t)n * G4 + (size_t)g * HH + jb) * BB + bh * 16 + bcol];
                float ci = cs[u * 32 + bh * 16 + bcol];
                float cn = sigm(g4[1]) * ci + sigm(g4[0]) * tanhf(g4[2]);
                cs[u * 32 + bh * 16 + bcol] = cn;
                ht[((size_t)(np * 2 + bh) * HH + jb) * 16 + bcol] = sigm(g4[3]) * tanhf(cn);
            }
        }
        // grid barrier (monotonic counter; device-scope fences)
        __syncthreads();
        __threadfence();
        if (tid == 0) {
            atomicAdd(bar, 1);
            int target = NBLK * (n + 1);
            while (atomicAdd(bar, 0) < target) __builtin_amdgcn_s_sleep(16);
        }
        __syncthreads();
        __threadfence();
    }
}

// ---------------- plan-side e1 bias (plan in ht[0][bh][k][16] layout) ----------------
__global__ void k_pb(const float* __restrict__ ht, const float* __restrict__ e1at,
                     const float* __restrict__ e1b, float* __restrict__ pb) {
    __shared__ float ps[HH];
    int b = blockIdx.y;
    int bh = b >> 4, bc = b & 15;
    for (int idx = threadIdx.x; idx < HH; idx += 256)
        ps[idx] = ht[((size_t)bh * HH + idx) * 16 + bc];
    __syncthreads();
    int o = blockIdx.x * 256 + threadIdx.x;
    if (o >= EV1) return;
    float acc = e1b[o];
    for (int k = 0; k < HH; k++) acc += ps[k] * e1at[(size_t)k * EV1 + o];
    pb[b * EV1 + o] = acc;
}

// ---------------- fused e3 + e4 tail ----------------
__global__ void k_e34(const float* __restrict__ e2out, const float* __restrict__ e3t,
                      const float* __restrict__ e3b, const float* __restrict__ e4w,
                      const float* __restrict__ e4b, float* __restrict__ out) {
    __shared__ float wt[EV2 * EV3];
    for (int idx = threadIdx.x; idx < EV2 * EV3; idx += 256) wt[idx] = e3t[idx];
    __syncthreads();
    int r = blockIdx.x * 256 + threadIdx.x;
    if (r >= ROWS) return;
    float h3[EV3];
#pragma unroll
    for (int o3 = 0; o3 < EV3; o3++) h3[o3] = e3b[o3];
    for (int k = 0; k < EV2; k++) {
        float v = e2out[(size_t)r * EV2 + k];
#pragma unroll
        for (int o3 = 0; o3 < EV3; o3++) h3[o3] += v * wt[k * EV3 + o3];
    }
    float acc = e4b[0];
#pragma unroll
    for (int o3 = 0; o3 < EV3; o3++) acc += fmaxf(h3[o3], 0.f) * e4w[o3];
    out[r] = fmaxf(acc, 0.f);
}

// ---------------- host launch ----------------
extern "C" void kernel_launch(void* const* d_in, const int* in_sizes, int n_in,
                              void* d_out, int out_size, void* d_ws, size_t ws_size,
                              hipStream_t stream) {
    const float* x    = (const float*)d_in[0];
    const float* w_ih = (const float*)d_in[1];
    const float* w_hh = (const float*)d_in[2];
    const float* b_ih = (const float*)d_in[3];
    const float* b_hh = (const float*)d_in[4];
    const float* q1_w = (const float*)d_in[5];
    const float* q1_b = (const float*)d_in[6];
    const float* q2_w = (const float*)d_in[7];
    const float* q2_b = (const float*)d_in[8];
    const float* e1_w = (const float*)d_in[9];
    const float* e1_b = (const float*)d_in[10];
    const float* e2_w = (const float*)d_in[11];
    const float* e2_b = (const float*)d_in[12];
    const float* e3_w = (const float*)d_in[13];
    const float* e3_b = (const float*)d_in[14];
    const float* e4_w = (const float*)d_in[15];
    const float* e4_b = (const float*)d_in[16];
    float* out = (float*)d_out;
    float* ws = (float*)d_ws;

    // workspace layout (float offsets)
    size_t off = 0;
    float* seq    = ws + off; off += (size_t)NN * BB * EE;          // 262,144
    size_t regionA = off; off += 17700000;
    // regionA phases:
    //  pre-LSTM : xg [0, 6.15M)
    //  pairs/q1 : pairs [0,8.13M) | q1out [8.13M,17.66M)   (xg dead after xgT)
    //  e1       : e1out [0,15.87M)                          (pairs,q1out dead)
    float* xg     = ws + regionA;                                   // 6,144,000
    float* pairs  = ws + regionA;                                   // 8,126,464
    float* q1out  = ws + regionA + 8130000;                         // 9,523,200
    float* e1out  = ws + regionA;                                   // 15,872,000
    float* xgT    = ws + off; off += (size_t)NN * G4 * BB;          // 6,144,000
    float* ht     = ws + off; off += 2 * 2 * HH * 16;               // 96,000 (ping-pong, b-halved)
    float* wih_t  = ws + off; off += (size_t)EE * G4;               // 1,536,000
    float* q1t    = ws + off; off += (size_t)QIN * Q1O;
    float* q1beff = ws + off; off += 1024;
    float* bsum   = ws + off; off += G4;
    float* q2t    = ws + off; off += (size_t)Q1O * QO;
    float* e1at   = ws + off; off += (size_t)HH * EV1;
    float* e1bt   = ws + off; off += (size_t)QO * EV1;
    float* e2t    = ws + off; off += (size_t)EV1 * EV2;
    float* e3t    = ws + off; off += 1024;
    float* pb     = ws + off; off += BB * EV1;
    float* q2out  = ws + off; off += (size_t)ROWS * QO;
    float* e2out  = ws + off; off += (size_t)ROWS * EV2;
    int*   iijj   = (int*)(ws + off); off += 1024;
    int*   bar    = (int*)(ws + off); off += 256;

    dim3 tb(32, 8);

    // init
    k_iijj<<<1, 512, 0, stream>>>(iijj);
    k_q1beff<<<3, 256, 0, stream>>>(q1_w, q1_b, q1beff);
    k_addb<<<24, 256, 0, stream>>>(b_ih, b_hh, bsum, G4);
    k_zero<<<376, 256, 0, stream>>>(ht, 2 * 2 * HH * 16);
    k_zero<<<1, 256, 0, stream>>>((float*)bar, 64);

    // weight transforms
    k_transpose<<<dim3(8, 188), tb, 0, stream>>>(w_ih, wih_t, G4, EE, 0, EE);
    k_transpose<<<dim3(16, 19), tb, 0, stream>>>(q1_w, q1t, Q1O, QIN, 0, QIN);
    k_transpose<<<dim3(19, 10), tb, 0, stream>>>(q2_w, q2t, QO, Q1O, 0, Q1O);
    k_transpose<<<dim3(47, 32), tb, 0, stream>>>(e1_w, e1at, EV1, HH + QO, 0, HH);
    k_transpose<<<dim3(10, 32), tb, 0, stream>>>(e1_w, e1bt, EV1, HH + QO, HH, QO);
    k_transpose<<<dim3(32, 4), tb, 0, stream>>>(e2_w, e2t, EV2, EV1, 0, EV1);
    k_transpose<<<dim3(4, 1), tb, 0, stream>>>(e3_w, e3t, EV3, EV2, 0, EV2);

    // sort + x-side gates (xg = seq @ wih_t + bsum), then transpose to [n][j][b]
    k_sort<<<32, 256, 0, stream>>>(x, seq);
    k_gemm<<<dim3(94, 16), 256, 0, stream>>>(seq, wih_t, bsum, nullptr, xg, 1024, EE, G4, 0);
    k_xgt<<<dim3(188, 1, 32), tb, 0, stream>>>(xg, xgT);

    // LSTM: single persistent kernel, 32 steps with internal grid barrier
    k_lstm_persist<<<NBLK, 512, 0, stream>>>(w_hh, xgT, ht, bar);

    // evaluator plan-side bias (plan = ht buffer 0 after 32 steps)
    k_pb<<<dim3(4, BB), 256, 0, stream>>>(ht, e1at, e1_b, pb);

    // pair MLP
    k_pairs<<<7936, 256, 0, stream>>>(x, iijj, pairs);
    k_gemm<<<dim3(10, 248), 256, 0, stream>>>(pairs, q1t, q1beff, nullptr, q1out, ROWS, QIN, Q1O, 1);
    k_gemm<<<dim3(5, 248), 256, 0, stream>>>(q1out, q2t, q2_b, nullptr, q2out, ROWS, Q1O, QO, 1);
    k_gemm<<<dim3(16, 248), 256, 0, stream>>>(q2out, e1bt, nullptr, pb, e1out, ROWS, QO, EV1, 1);
    k_gemm<<<dim3(2, 248), 256, 0, stream>>>(e1out, e2t, e2_b, nullptr, e2out, ROWS, EV1, EV2, 1);
    k_e34<<<62, 256, 0, stream>>>(e2out, e3t, e3_b, e4_w, e4_b, out);
}

// Round 6
// 4092.432 us; speedup vs baseline: 1.0946x; 1.0931x over previous
//
#include <hip/hip_runtime.h>
#include <math.h>

// Problem dims
#define BB 32
#define NN 32
#define EE 256
#define HH 1500
#define G4 6000      // 4*HH
#define QIN 512
#define Q1O 600
#define QO 300
#define EV1 1000
#define EV2 100
#define EV3 10
#define PP 496       // N*(N-1)/2
#define ROWS (BB*PP) // 15872
#define BH (BB*HH)   // 48000

// persistent LSTM config
#define NBLK 250     // blocks (<=256 CUs, all resident)
#define JHB 6        // hidden units per block (250*6 = 1500)
#define TSL 24       // weight t-slots per thread (24*64 = 1536 >= 1500)
#define CKK 768      // k-chunk staged in LDS (2 chunks cover 1536)
#define HSTR 12      // hs row stride in floats (8 data + 4 pad; 12-stride -> uniform banks)

__device__ __forceinline__ float sigm(float x) { return 1.f / (1.f + expf(-x)); }

// ---------------- init helpers ----------------
__global__ void k_zero(float* a, int n) {
    int i = blockIdx.x * 256 + threadIdx.x;
    if (i < n) a[i] = 0.f;
}

__global__ void k_iijj(int* iijj) {
    int p = threadIdx.x;
    if (p >= PP) return;
    int i = 0, p0 = 0;
    while (p >= p0 + (NN - 1 - i)) { p0 += NN - 1 - i; i++; }
    iijj[p] = i;
    iijj[PP + p] = i + 1 + (p - p0);
}

// q1 effective bias: q1_b[o] + sum over odd k of q1_w[o][k]  (PE at pos 0)
__global__ void k_q1beff(const float* q1w, const float* q1b, float* beff) {
    int o = blockIdx.x * 256 + threadIdx.x;
    if (o >= Q1O) return;
    float a = q1b[o];
    for (int k = 1; k < QIN; k += 2) a += q1w[o * QIN + k];
    beff[o] = a;
}

__global__ void k_addb(const float* a, const float* b, float* c, int n) {
    int i = blockIdx.x * 256 + threadIdx.x;
    if (i < n) c[i] = a[i] + b[i];
}

// ---------------- transpose (sub-range of columns) ----------------
__global__ void k_transpose(const float* __restrict__ src, float* __restrict__ dst,
                            int R, int C, int c0, int csub) {
    __shared__ float tile[32][33];
    int cb = blockIdx.x * 32, rb = blockIdx.y * 32;
    for (int dy = threadIdx.y; dy < 32; dy += 8) {
        int r = rb + dy, c = cb + threadIdx.x;
        if (r < R && c < csub) tile[dy][threadIdx.x] = src[(size_t)r * C + c0 + c];
    }
    __syncthreads();
    for (int dy = threadIdx.y; dy < 32; dy += 8) {
        int c = cb + dy, r = rb + threadIdx.x;
        if (c < csub && r < R) dst[(size_t)c * R + r] = tile[threadIdx.x][dy];
    }
}

// ---------------- sort along parts axis ----------------
__global__ void k_sort(const float* __restrict__ x, float* __restrict__ seq) {
    int tid = blockIdx.x * 256 + threadIdx.x;
    if (tid >= BB * EE) return;
    int b = tid / EE, e = tid % EE;
    float v[NN];
    for (int n = 0; n < NN; n++) v[n] = x[(b * NN + n) * EE + e];
    for (int i = 1; i < NN; i++) {
        float key = v[i];
        int j = i - 1;
        while (j >= 0 && v[j] > key) { v[j + 1] = v[j]; j--; }
        v[j + 1] = key;
    }
    for (int n = 0; n < NN; n++) seq[(n * BB + b) * EE + e] = v[n];
}

// ---------------- transpose xg[(n*32+b)][j] -> xgT[n][j][b] ----------------
__global__ void k_xgt(const float* __restrict__ xg, float* __restrict__ xgT) {
    __shared__ float t[32][33];
    int n = blockIdx.z;
    int j0 = blockIdx.x * 32;
    for (int dy = threadIdx.y; dy < 32; dy += 8) {
        int j = j0 + threadIdx.x;
        if (j < G4) t[dy][threadIdx.x] = xg[(size_t)(n * 32 + dy) * G4 + j];
    }
    __syncthreads();
    for (int dy = threadIdx.y; dy < 32; dy += 8) {
        int j = j0 + dy;
        if (j < G4) xgT[(size_t)n * (G4 * BB) + (size_t)j * BB + threadIdx.x] = t[threadIdx.x][dy];
    }
}

// ---------------- pairs gather ----------------
__global__ void k_pairs(const float* __restrict__ x, const int* __restrict__ iijj,
                        float* __restrict__ pairs) {
    int idx = blockIdx.x * 256 + threadIdx.x; // quad index
    int r = idx >> 7;
    if (r >= ROWS) return;
    int q = idx & 127, k = q << 2;
    int b = r / PP, p = r - b * PP;
    int part = (k < EE) ? iijj[p] : iijj[PP + p];
    float4 v = *(const float4*)(x + (size_t)(b * NN + part) * EE + (k & (EE - 1)));
    *(float4*)(pairs + (size_t)r * QIN + k) = v;
}

// ---------------- tiled GEMM: C[M][N] = act(A[M][K] @ Bw[K][N] + bias + pb) ----------------
__global__ void k_gemm(const float* __restrict__ A, const float* __restrict__ Bw,
                       const float* __restrict__ bias, const float* __restrict__ pbm,
                       float* __restrict__ C, int M, int K, int N, int relu) {
    __shared__ __align__(16) float As[16][68];
    __shared__ __align__(16) float Bs[16][64];
    int tid = threadIdx.x;
    int m0 = blockIdx.y * 64, n0 = blockIdx.x * 64;
    int am = tid >> 2, ak4 = (tid & 3) << 2;
    int bk = tid >> 4, bn4 = (tid & 15) << 2;
    int tm = tid >> 4, tn = tid & 15;
    float acc[4][4] = {{0.f}};
    for (int k0 = 0; k0 < K; k0 += 16) {
        float4 av = {0.f, 0.f, 0.f, 0.f};
        if (k0 + ak4 < K) av = *(const float4*)(A + (size_t)(m0 + am) * K + k0 + ak4);
        float4 bv = {0.f, 0.f, 0.f, 0.f};
        if (k0 + bk < K && n0 + bn4 < N) bv = *(const float4*)(Bw + (size_t)(k0 + bk) * N + n0 + bn4);
        __syncthreads();
        As[ak4 + 0][am] = av.x; As[ak4 + 1][am] = av.y;
        As[ak4 + 2][am] = av.z; As[ak4 + 3][am] = av.w;
        *(float4*)&Bs[bk][bn4] = bv;
        __syncthreads();
#pragma unroll
        for (int kk = 0; kk < 16; kk++) {
            float4 a = *(const float4*)&As[kk][tm << 2];
            float4 b = *(const float4*)&Bs[kk][tn << 2];
            acc[0][0] += a.x * b.x; acc[0][1] += a.x * b.y; acc[0][2] += a.x * b.z; acc[0][3] += a.x * b.w;
            acc[1][0] += a.y * b.x; acc[1][1] += a.y * b.y; acc[1][2] += a.y * b.z; acc[1][3] += a.y * b.w;
            acc[2][0] += a.z * b.x; acc[2][1] += a.z * b.y; acc[2][2] += a.z * b.z; acc[2][3] += a.z * b.w;
            acc[3][0] += a.w * b.x; acc[3][1] += a.w * b.y; acc[3][2] += a.w * b.z; acc[3][3] += a.w * b.w;
        }
    }
    int col0 = n0 + (tn << 2);
    if (col0 >= N) return;
    float4 bb0 = {0.f, 0.f, 0.f, 0.f};
    if (bias) bb0 = *(const float4*)(bias + col0);
#pragma unroll
    for (int i = 0; i < 4; i++) {
        int row = m0 + (tm << 2) + i;
        float4 pv = {0.f, 0.f, 0.f, 0.f};
        if (pbm) pv = *(const float4*)(pbm + (size_t)(row / PP) * N + col0);
        float4 r;
        r.x = acc[i][0] + bb0.x + pv.x;
        r.y = acc[i][1] + bb0.y + pv.y;
        r.z = acc[i][2] + bb0.z + pv.z;
        r.w = acc[i][3] + bb0.w + pv.w;
        if (relu) {
            r.x = fmaxf(r.x, 0.f); r.y = fmaxf(r.y, 0.f);
            r.z = fmaxf(r.z, 0.f); r.w = fmaxf(r.w, 0.f);
        }
        *(float4*)(C + (size_t)row * N + col0) = r;
    }
}

// ---------------- persistent LSTM: all 32 steps in one kernel ----------------
// 250 blocks x 512 threads, all resident. Each block owns 6 hidden units
// (24 gate rows); wave w owns rows {3w,3w+1,3w+2}; lane l is the k-interleave.
// wreg[3][24] (72 VGPRs) holds the thread's w_hh slice -- ALL indices into
// wreg/acc are compile-time constants (R4/R5 bug: runtime chunk index forced
// wreg into scratch -> 36MB re-read per step, 1.05 GB FETCH/dispatch).
// Batch processed in 4 octets (acc[3][8]=24 regs): total live ~115 < 128 cap.
// ht layout: [pingpong][k][32 batches]. LDS hs[768][12]: stride 12 gives
// uniform 8-per-bank access for float4 reads/writes (m136: 2-way free).
__global__ __attribute__((amdgpu_waves_per_eu(2))) __launch_bounds__(512)
void k_lstm_persist(const float* __restrict__ whh, const float* __restrict__ xgT,
                    float* __restrict__ ht, int* __restrict__ bar) {
    __shared__ __align__(16) float hs[CKK * HSTR];  // 36864 B
    __shared__ float red[24 * 8];                   // 768 B
    __shared__ float cs[JHB * BB];                  // 768 B
    const int tid = threadIdx.x;
    const int w = tid >> 6;   // wave = row-group of 3
    const int l = tid & 63;   // lane = k offset
    const int jh0 = blockIdx.x * JHB;

    // one-time weight load (coalesced: consecutive lanes -> consecutive k)
    float wreg[3][TSL];
#pragma unroll
    for (int i = 0; i < 3; i++) {
        int r = w * 3 + i;                 // r = g*JHB + u
        int g = r / JHB, u = r - g * JHB;
        const float* wr = whh + (size_t)(g * HH + jh0 + u) * HH;
#pragma unroll
        for (int t = 0; t < TSL; t++) {
            int k = (t << 6) + l;
            wreg[i][t] = (k < HH) ? wr[k] : 0.f;
        }
    }
    for (int idx = tid; idx < JHB * BB; idx += 512) cs[idx] = 0.f;
    __syncthreads();

    for (int n = 0; n < NN; n++) {
        const int pp = n & 1, np = pp ^ 1;
        const float* hsrc = ht + (size_t)pp * BH;
        float* hdst = ht + (size_t)np * BH;
#pragma unroll 1
        for (int o = 0; o < 4; o++) {
            const int b0 = o * 8;
            float acc[3][8];
#pragma unroll
            for (int i = 0; i < 3; i++)
#pragma unroll
                for (int b = 0; b < 8; b++) acc[i][b] = 0.f;
#pragma unroll
            for (int c = 0; c < 2; c++) {          // MUST be fully unrolled (wreg index)
                __syncthreads();  // hs reuse safe
                for (int fi = tid; fi < CKK * 2; fi += 512) {
                    int kk = fi >> 1, hf = fi & 1;
                    int k = c * CKK + kk;
                    float4 v = {0.f, 0.f, 0.f, 0.f};
                    if (k < HH) v = *(const float4*)(hsrc + (size_t)k * BB + b0 + (hf << 2));
                    *(float4*)&hs[kk * HSTR + (hf << 2)] = v;
                }
                __syncthreads();
#pragma unroll
                for (int t = 0; t < 12; t++) {
                    const float* hp = &hs[((t << 6) + l) * HSTR];
                    float4 ha = *(const float4*)hp;
                    float4 hb = *(const float4*)(hp + 4);
#pragma unroll
                    for (int i = 0; i < 3; i++) {
                        float wv = wreg[i][c * 12 + t];
                        acc[i][0] += wv * ha.x; acc[i][1] += wv * ha.y;
                        acc[i][2] += wv * ha.z; acc[i][3] += wv * ha.w;
                        acc[i][4] += wv * hb.x; acc[i][5] += wv * hb.y;
                        acc[i][6] += wv * hb.z; acc[i][7] += wv * hb.w;
                    }
                }
            }
            // butterfly reduce the 64-lane k-split
#pragma unroll
            for (int off = 32; off >= 1; off >>= 1)
#pragma unroll
                for (int i = 0; i < 3; i++)
#pragma unroll
                    for (int b = 0; b < 8; b++)
                        acc[i][b] += __shfl_xor(acc[i][b], off);
            if (l == 0) {
#pragma unroll
                for (int i = 0; i < 3; i++)
#pragma unroll
                    for (int b = 0; b < 8; b++)
                        red[(w * 3 + i) * 8 + b] = acc[i][b];
            }
            __syncthreads();
            // gate nonlinearity for this octet
            if (tid < JHB * 8) {
                int u = tid >> 3, bc = tid & 7;
                int jb = jh0 + u;
                float g4[4];
#pragma unroll
                for (int g = 0; g < 4; g++)
                    g4[g] = red[(g * JHB + u) * 8 + bc]
                          + xgT[((size_t)n * G4 + (size_t)g * HH + jb) * BB + b0 + bc];
                float ci = cs[u * BB + b0 + bc];
                float cn = sigm(g4[1]) * ci + sigm(g4[0]) * tanhf(g4[2]);
                cs[u * BB + b0 + bc] = cn;
                hdst[(size_t)jb * BB + b0 + bc] = sigm(g4[3]) * tanhf(cn);
            }
        }
        // grid barrier (monotonic counter; device-scope fences)
        __syncthreads();
        __threadfence();
        if (tid == 0) {
            atomicAdd(bar, 1);
            int target = NBLK * (n + 1);
            while (atomicAdd(bar, 0) < target) __builtin_amdgcn_s_sleep(16);
        }
        __syncthreads();
        __threadfence();
    }
}

// ---------------- plan-side e1 bias (plan = ht buffer 0, layout [k][32]) ----------------
__global__ void k_pb(const float* __restrict__ ht, const float* __restrict__ e1at,
                     const float* __restrict__ e1b, float* __restrict__ pb) {
    __shared__ float ps[HH];
    int b = blockIdx.y;
    for (int idx = threadIdx.x; idx < HH; idx += 256)
        ps[idx] = ht[(size_t)idx * BB + b];
    __syncthreads();
    int o = blockIdx.x * 256 + threadIdx.x;
    if (o >= EV1) return;
    float acc = e1b[o];
    for (int k = 0; k < HH; k++) acc += ps[k] * e1at[(size_t)k * EV1 + o];
    pb[b * EV1 + o] = acc;
}

// ---------------- fused e3 + e4 tail ----------------
__global__ void k_e34(const float* __restrict__ e2out, const float* __restrict__ e3t,
                      const float* __restrict__ e3b, const float* __restrict__ e4w,
                      const float* __restrict__ e4b, float* __restrict__ out) {
    __shared__ float wt[EV2 * EV3];
    for (int idx = threadIdx.x; idx < EV2 * EV3; idx += 256) wt[idx] = e3t[idx];
    __syncthreads();
    int r = blockIdx.x * 256 + threadIdx.x;
    if (r >= ROWS) return;
    float h3[EV3];
#pragma unroll
    for (int o3 = 0; o3 < EV3; o3++) h3[o3] = e3b[o3];
    for (int k = 0; k < EV2; k++) {
        float v = e2out[(size_t)r * EV2 + k];
#pragma unroll
        for (int o3 = 0; o3 < EV3; o3++) h3[o3] += v * wt[k * EV3 + o3];
    }
    float acc = e4b[0];
#pragma unroll
    for (int o3 = 0; o3 < EV3; o3++) acc += fmaxf(h3[o3], 0.f) * e4w[o3];
    out[r] = fmaxf(acc, 0.f);
}

// ---------------- host launch ----------------
extern "C" void kernel_launch(void* const* d_in, const int* in_sizes, int n_in,
                              void* d_out, int out_size, void* d_ws, size_t ws_size,
                              hipStream_t stream) {
    const float* x    = (const float*)d_in[0];
    const float* w_ih = (const float*)d_in[1];
    const float* w_hh = (const float*)d_in[2];
    const float* b_ih = (const float*)d_in[3];
    const float* b_hh = (const float*)d_in[4];
    const float* q1_w = (const float*)d_in[5];
    const float* q1_b = (const float*)d_in[6];
    const float* q2_w = (const float*)d_in[7];
    const float* q2_b = (const float*)d_in[8];
    const float* e1_w = (const float*)d_in[9];
    const float* e1_b = (const float*)d_in[10];
    const float* e2_w = (const float*)d_in[11];
    const float* e2_b = (const float*)d_in[12];
    const float* e3_w = (const float*)d_in[13];
    const float* e3_b = (const float*)d_in[14];
    const float* e4_w = (const float*)d_in[15];
    const float* e4_b = (const float*)d_in[16];
    float* out = (float*)d_out;
    float* ws = (float*)d_ws;

    // workspace layout (float offsets)
    size_t off = 0;
    float* seq    = ws + off; off += (size_t)NN * BB * EE;          // 262,144
    size_t regionA = off; off += 17700000;
    // regionA phases:
    //  pre-LSTM : xg [0, 6.15M)
    //  pairs/q1 : pairs [0,8.13M) | q1out [8.13M,17.66M)   (xg dead after xgT)
    //  e1       : e1out [0,15.87M)                          (pairs,q1out dead)
    float* xg     = ws + regionA;                                   // 6,144,000
    float* pairs  = ws + regionA;                                   // 8,126,464
    float* q1out  = ws + regionA + 8130000;                         // 9,523,200
    float* e1out  = ws + regionA;                                   // 15,872,000
    float* xgT    = ws + off; off += (size_t)NN * G4 * BB;          // 6,144,000
    float* ht     = ws + off; off += 2 * BH;                        // 96,000 (ping-pong [2][1500][32])
    float* wih_t  = ws + off; off += (size_t)EE * G4;               // 1,536,000
    float* q1t    = ws + off; off += (size_t)QIN * Q1O;
    float* q1beff = ws + off; off += 1024;
    float* bsum   = ws + off; off += G4;
    float* q2t    = ws + off; off += (size_t)Q1O * QO;
    float* e1at   = ws + off; off += (size_t)HH * EV1;
    float* e1bt   = ws + off; off += (size_t)QO * EV1;
    float* e2t    = ws + off; off += (size_t)EV1 * EV2;
    float* e3t    = ws + off; off += 1024;
    float* pb     = ws + off; off += BB * EV1;
    float* q2out  = ws + off; off += (size_t)ROWS * QO;
    float* e2out  = ws + off; off += (size_t)ROWS * EV2;
    int*   iijj   = (int*)(ws + off); off += 1024;
    int*   bar    = (int*)(ws + off); off += 256;

    dim3 tb(32, 8);

    // init
    k_iijj<<<1, 512, 0, stream>>>(iijj);
    k_q1beff<<<3, 256, 0, stream>>>(q1_w, q1_b, q1beff);
    k_addb<<<24, 256, 0, stream>>>(b_ih, b_hh, bsum, G4);
    k_zero<<<376, 256, 0, stream>>>(ht, 2 * BH);
    k_zero<<<1, 256, 0, stream>>>((float*)bar, 64);

    // weight transforms
    k_transpose<<<dim3(8, 188), tb, 0, stream>>>(w_ih, wih_t, G4, EE, 0, EE);
    k_transpose<<<dim3(16, 19), tb, 0, stream>>>(q1_w, q1t, Q1O, QIN, 0, QIN);
    k_transpose<<<dim3(19, 10), tb, 0, stream>>>(q2_w, q2t, QO, Q1O, 0, Q1O);
    k_transpose<<<dim3(47, 32), tb, 0, stream>>>(e1_w, e1at, EV1, HH + QO, 0, HH);
    k_transpose<<<dim3(10, 32), tb, 0, stream>>>(e1_w, e1bt, EV1, HH + QO, HH, QO);
    k_transpose<<<dim3(32, 4), tb, 0, stream>>>(e2_w, e2t, EV2, EV1, 0, EV1);
    k_transpose<<<dim3(4, 1), tb, 0, stream>>>(e3_w, e3t, EV3, EV2, 0, EV2);

    // sort + x-side gates (xg = seq @ wih_t + bsum), then transpose to [n][j][b]
    k_sort<<<32, 256, 0, stream>>>(x, seq);
    k_gemm<<<dim3(94, 16), 256, 0, stream>>>(seq, wih_t, bsum, nullptr, xg, 1024, EE, G4, 0);
    k_xgt<<<dim3(188, 1, 32), tb, 0, stream>>>(xg, xgT);

    // LSTM: single persistent kernel, 32 steps with internal grid barrier
    k_lstm_persist<<<NBLK, 512, 0, stream>>>(w_hh, xgT, ht, bar);

    // evaluator plan-side bias (plan = ht buffer 0 after 32 steps)
    k_pb<<<dim3(4, BB), 256, 0, stream>>>(ht, e1at, e1_b, pb);

    // pair MLP
    k_pairs<<<7936, 256, 0, stream>>>(x, iijj, pairs);
    k_gemm<<<dim3(10, 248), 256, 0, stream>>>(pairs, q1t, q1beff, nullptr, q1out, ROWS, QIN, Q1O, 1);
    k_gemm<<<dim3(5, 248), 256, 0, stream>>>(q1out, q2t, q2_b, nullptr, q2out, ROWS, Q1O, QO, 1);
    k_gemm<<<dim3(16, 248), 256, 0, stream>>>(q2out, e1bt, nullptr, pb, e1out, ROWS, QO, EV1, 1);
    k_gemm<<<dim3(2, 248), 256, 0, stream>>>(e1out, e2t, e2_b, nullptr, e2out, ROWS, EV1, EV2, 1);
    k_e34<<<62, 256, 0, stream>>>(e2out, e3t, e3_b, e4_w, e4_b, out);
}

// Round 7
// 2552.502 us; speedup vs baseline: 1.7550x; 1.6033x over previous
//
#include <hip/hip_runtime.h>
#include <math.h>

// Problem dims
#define BB 32
#define NN 32
#define EE 256
#define HH 1500
#define G4 6000      // 4*HH
#define QIN 512
#define Q1O 600
#define QO 300
#define EV1 1000
#define EV2 100
#define EV3 10
#define PP 496       // N*(N-1)/2
#define ROWS (BB*PP) // 15872
#define BH (BB*HH)   // 48000

// persistent LSTM config
#define NBLK 250     // blocks (<=256 CUs, all resident)
#define JHB 6        // hidden units per block (250*6 = 1500)
#define TSL 24       // weight t-slots per thread (24*64 = 1536 >= 1500)
#define CKK 768      // k-chunk staged in LDS (2 chunks cover 1536)
#define HSTR 12      // hs row stride in floats (8 data + 4 pad; uniform 8/bank = b128 floor)

__device__ __forceinline__ float sigm(float x) { return 1.f / (1.f + expf(-x)); }

// ---------------- init helpers ----------------
__global__ void k_zero(float* a, int n) {
    int i = blockIdx.x * 256 + threadIdx.x;
    if (i < n) a[i] = 0.f;
}

__global__ void k_iijj(int* iijj) {
    int p = threadIdx.x;
    if (p >= PP) return;
    int i = 0, p0 = 0;
    while (p >= p0 + (NN - 1 - i)) { p0 += NN - 1 - i; i++; }
    iijj[p] = i;
    iijj[PP + p] = i + 1 + (p - p0);
}

// q1 effective bias: q1_b[o] + sum over odd k of q1_w[o][k]  (PE at pos 0)
__global__ void k_q1beff(const float* q1w, const float* q1b, float* beff) {
    int o = blockIdx.x * 256 + threadIdx.x;
    if (o >= Q1O) return;
    float a = q1b[o];
    for (int k = 1; k < QIN; k += 2) a += q1w[o * QIN + k];
    beff[o] = a;
}

__global__ void k_addb(const float* a, const float* b, float* c, int n) {
    int i = blockIdx.x * 256 + threadIdx.x;
    if (i < n) c[i] = a[i] + b[i];
}

// ---------------- transpose (sub-range of columns) ----------------
__global__ void k_transpose(const float* __restrict__ src, float* __restrict__ dst,
                            int R, int C, int c0, int csub) {
    __shared__ float tile[32][33];
    int cb = blockIdx.x * 32, rb = blockIdx.y * 32;
    for (int dy = threadIdx.y; dy < 32; dy += 8) {
        int r = rb + dy, c = cb + threadIdx.x;
        if (r < R && c < csub) tile[dy][threadIdx.x] = src[(size_t)r * C + c0 + c];
    }
    __syncthreads();
    for (int dy = threadIdx.y; dy < 32; dy += 8) {
        int c = cb + dy, r = rb + threadIdx.x;
        if (c < csub && r < R) dst[(size_t)c * R + r] = tile[threadIdx.x][dy];
    }
}

// ---------------- sort along parts axis ----------------
__global__ void k_sort(const float* __restrict__ x, float* __restrict__ seq) {
    int tid = blockIdx.x * 256 + threadIdx.x;
    if (tid >= BB * EE) return;
    int b = tid / EE, e = tid % EE;
    float v[NN];
    for (int n = 0; n < NN; n++) v[n] = x[(b * NN + n) * EE + e];
    for (int i = 1; i < NN; i++) {
        float key = v[i];
        int j = i - 1;
        while (j >= 0 && v[j] > key) { v[j + 1] = v[j]; j--; }
        v[j + 1] = key;
    }
    for (int n = 0; n < NN; n++) seq[(n * BB + b) * EE + e] = v[n];
}

// ---------------- transpose xg[(n*32+b)][j] -> xgT[n][j][b] ----------------
__global__ void k_xgt(const float* __restrict__ xg, float* __restrict__ xgT) {
    __shared__ float t[32][33];
    int n = blockIdx.z;
    int j0 = blockIdx.x * 32;
    for (int dy = threadIdx.y; dy < 32; dy += 8) {
        int j = j0 + threadIdx.x;
        if (j < G4) t[dy][threadIdx.x] = xg[(size_t)(n * 32 + dy) * G4 + j];
    }
    __syncthreads();
    for (int dy = threadIdx.y; dy < 32; dy += 8) {
        int j = j0 + dy;
        if (j < G4) xgT[(size_t)n * (G4 * BB) + (size_t)j * BB + threadIdx.x] = t[threadIdx.x][dy];
    }
}

// ---------------- pairs gather ----------------
__global__ void k_pairs(const float* __restrict__ x, const int* __restrict__ iijj,
                        float* __restrict__ pairs) {
    int idx = blockIdx.x * 256 + threadIdx.x; // quad index
    int r = idx >> 7;
    if (r >= ROWS) return;
    int q = idx & 127, k = q << 2;
    int b = r / PP, p = r - b * PP;
    int part = (k < EE) ? iijj[p] : iijj[PP + p];
    float4 v = *(const float4*)(x + (size_t)(b * NN + part) * EE + (k & (EE - 1)));
    *(float4*)(pairs + (size_t)r * QIN + k) = v;
}

// ---------------- tiled GEMM: C[M][N] = act(A[M][K] @ Bw[K][N] + bias + pb) ----------------
__global__ void k_gemm(const float* __restrict__ A, const float* __restrict__ Bw,
                       const float* __restrict__ bias, const float* __restrict__ pbm,
                       float* __restrict__ C, int M, int K, int N, int relu) {
    __shared__ __align__(16) float As[16][68];
    __shared__ __align__(16) float Bs[16][64];
    int tid = threadIdx.x;
    int m0 = blockIdx.y * 64, n0 = blockIdx.x * 64;
    int am = tid >> 2, ak4 = (tid & 3) << 2;
    int bk = tid >> 4, bn4 = (tid & 15) << 2;
    int tm = tid >> 4, tn = tid & 15;
    float acc[4][4] = {{0.f}};
    for (int k0 = 0; k0 < K; k0 += 16) {
        float4 av = {0.f, 0.f, 0.f, 0.f};
        if (k0 + ak4 < K) av = *(const float4*)(A + (size_t)(m0 + am) * K + k0 + ak4);
        float4 bv = {0.f, 0.f, 0.f, 0.f};
        if (k0 + bk < K && n0 + bn4 < N) bv = *(const float4*)(Bw + (size_t)(k0 + bk) * N + n0 + bn4);
        __syncthreads();
        As[ak4 + 0][am] = av.x; As[ak4 + 1][am] = av.y;
        As[ak4 + 2][am] = av.z; As[ak4 + 3][am] = av.w;
        *(float4*)&Bs[bk][bn4] = bv;
        __syncthreads();
#pragma unroll
        for (int kk = 0; kk < 16; kk++) {
            float4 a = *(const float4*)&As[kk][tm << 2];
            float4 b = *(const float4*)&Bs[kk][tn << 2];
            acc[0][0] += a.x * b.x; acc[0][1] += a.x * b.y; acc[0][2] += a.x * b.z; acc[0][3] += a.x * b.w;
            acc[1][0] += a.y * b.x; acc[1][1] += a.y * b.y; acc[1][2] += a.y * b.z; acc[1][3] += a.y * b.w;
            acc[2][0] += a.z * b.x; acc[2][1] += a.z * b.y; acc[2][2] += a.z * b.z; acc[2][3] += a.z * b.w;
            acc[3][0] += a.w * b.x; acc[3][1] += a.w * b.y; acc[3][2] += a.w * b.z; acc[3][3] += a.w * b.w;
        }
    }
    int col0 = n0 + (tn << 2);
    if (col0 >= N) return;
    float4 bb0 = {0.f, 0.f, 0.f, 0.f};
    if (bias) bb0 = *(const float4*)(bias + col0);
#pragma unroll
    for (int i = 0; i < 4; i++) {
        int row = m0 + (tm << 2) + i;
        float4 pv = {0.f, 0.f, 0.f, 0.f};
        if (pbm) pv = *(const float4*)(pbm + (size_t)(row / PP) * N + col0);
        float4 r;
        r.x = acc[i][0] + bb0.x + pv.x;
        r.y = acc[i][1] + bb0.y + pv.y;
        r.z = acc[i][2] + bb0.z + pv.z;
        r.w = acc[i][3] + bb0.w + pv.w;
        if (relu) {
            r.x = fmaxf(r.x, 0.f); r.y = fmaxf(r.y, 0.f);
            r.z = fmaxf(r.z, 0.f); r.w = fmaxf(r.w, 0.f);
        }
        *(float4*)(C + (size_t)row * N + col0) = r;
    }
}

// ---------------- persistent LSTM: all 32 steps in one kernel ----------------
// 250 blocks x 512 threads, all resident. Weights register-resident (R6 fixed
// the scratch spill: FETCH 1.05GB -> 60MB). R6 residual bottleneck was the
// grid barrier: RMW-spin (atomicAdd(bar,0)) serialized 250 contenders at the
// coherence point (~100us/step; WRITE_SIZE 100MB of spin dirt). Now: arrive
// with scoped release fetch_add, spin on scoped ACQUIRE LOAD (no ownership,
// no serialization) — the cooperative-groups grid.sync pattern.
__global__ __attribute__((amdgpu_waves_per_eu(2))) __launch_bounds__(512)
void k_lstm_persist(const float* __restrict__ whh, const float* __restrict__ xgT,
                    float* __restrict__ ht, int* __restrict__ bar) {
    __shared__ __align__(16) float hs[CKK * HSTR];  // 36864 B
    __shared__ float red[24 * 8];                   // 768 B
    __shared__ float cs[JHB * BB];                  // 768 B
    const int tid = threadIdx.x;
    const int w = tid >> 6;   // wave = row-group of 3
    const int l = tid & 63;   // lane = k offset
    const int jh0 = blockIdx.x * JHB;

    // one-time weight load (coalesced: consecutive lanes -> consecutive k)
    float wreg[3][TSL];
#pragma unroll
    for (int i = 0; i < 3; i++) {
        int r = w * 3 + i;                 // r = g*JHB + u
        int g = r / JHB, u = r - g * JHB;
        const float* wr = whh + (size_t)(g * HH + jh0 + u) * HH;
#pragma unroll
        for (int t = 0; t < TSL; t++) {
            int k = (t << 6) + l;
            wreg[i][t] = (k < HH) ? wr[k] : 0.f;
        }
    }
    for (int idx = tid; idx < JHB * BB; idx += 512) cs[idx] = 0.f;
    __syncthreads();

    for (int n = 0; n < NN; n++) {
        const int pp = n & 1, np = pp ^ 1;
        const float* hsrc = ht + (size_t)pp * BH;
        float* hdst = ht + (size_t)np * BH;
#pragma unroll 1
        for (int o = 0; o < 4; o++) {
            const int b0 = o * 8;
            // prefetch gate-side xg early: latency hides under staging+FMA
            float xr[4];
            if (tid < JHB * 8) {
                int u = tid >> 3, bc = tid & 7;
                int jb = jh0 + u;
#pragma unroll
                for (int g = 0; g < 4; g++)
                    xr[g] = xgT[((size_t)n * G4 + (size_t)g * HH + jb) * BB + b0 + bc];
            }
            float acc[3][8];
#pragma unroll
            for (int i = 0; i < 3; i++)
#pragma unroll
                for (int b = 0; b < 8; b++) acc[i][b] = 0.f;
#pragma unroll
            for (int c = 0; c < 2; c++) {          // MUST be fully unrolled (wreg index)
                __syncthreads();  // hs reuse safe
                for (int fi = tid; fi < CKK * 2; fi += 512) {
                    int kk = fi >> 1, hf = fi & 1;
                    int k = c * CKK + kk;
                    float4 v = {0.f, 0.f, 0.f, 0.f};
                    if (k < HH) v = *(const float4*)(hsrc + (size_t)k * BB + b0 + (hf << 2));
                    *(float4*)&hs[kk * HSTR + (hf << 2)] = v;
                }
                __syncthreads();
#pragma unroll
                for (int t = 0; t < 12; t++) {
                    const float* hp = &hs[((t << 6) + l) * HSTR];
                    float4 ha = *(const float4*)hp;
                    float4 hb = *(const float4*)(hp + 4);
#pragma unroll
                    for (int i = 0; i < 3; i++) {
                        float wv = wreg[i][c * 12 + t];
                        acc[i][0] += wv * ha.x; acc[i][1] += wv * ha.y;
                        acc[i][2] += wv * ha.z; acc[i][3] += wv * ha.w;
                        acc[i][4] += wv * hb.x; acc[i][5] += wv * hb.y;
                        acc[i][6] += wv * hb.z; acc[i][7] += wv * hb.w;
                    }
                }
            }
            // butterfly reduce the 64-lane k-split
#pragma unroll
            for (int off = 32; off >= 1; off >>= 1)
#pragma unroll
                for (int i = 0; i < 3; i++)
#pragma unroll
                    for (int b = 0; b < 8; b++)
                        acc[i][b] += __shfl_xor(acc[i][b], off);
            if (l == 0) {
#pragma unroll
                for (int i = 0; i < 3; i++)
#pragma unroll
                    for (int b = 0; b < 8; b++)
                        red[(w * 3 + i) * 8 + b] = acc[i][b];
            }
            __syncthreads();
            // gate nonlinearity for this octet
            if (tid < JHB * 8) {
                int u = tid >> 3, bc = tid & 7;
                int jb = jh0 + u;
                float g4[4];
#pragma unroll
                for (int g = 0; g < 4; g++)
                    g4[g] = red[(g * JHB + u) * 8 + bc] + xr[g];
                float ci = cs[u * BB + b0 + bc];
                float cn = sigm(g4[1]) * ci + sigm(g4[0]) * tanhf(g4[2]);
                cs[u * BB + b0 + bc] = cn;
                hdst[(size_t)jb * BB + b0 + bc] = sigm(g4[3]) * tanhf(cn);
            }
        }
        // grid barrier: release-add arrive, ACQUIRE-LOAD spin (no RMW storm)
        __syncthreads();
        if (tid == 0) {
            __hip_atomic_fetch_add(bar, 1, __ATOMIC_ACQ_REL, __HIP_MEMORY_SCOPE_AGENT);
            const int target = NBLK * (n + 1);
            while (__hip_atomic_load(bar, __ATOMIC_ACQUIRE, __HIP_MEMORY_SCOPE_AGENT) < target)
                __builtin_amdgcn_s_sleep(2);
        }
        __syncthreads();
    }
}

// ---------------- plan-side e1 bias (plan = ht buffer 0, layout [k][32]) ----------------
__global__ void k_pb(const float* __restrict__ ht, const float* __restrict__ e1at,
                     const float* __restrict__ e1b, float* __restrict__ pb) {
    __shared__ float ps[HH];
    int b = blockIdx.y;
    for (int idx = threadIdx.x; idx < HH; idx += 256)
        ps[idx] = ht[(size_t)idx * BB + b];
    __syncthreads();
    int o = blockIdx.x * 256 + threadIdx.x;
    if (o >= EV1) return;
    float acc = e1b[o];
    for (int k = 0; k < HH; k++) acc += ps[k] * e1at[(size_t)k * EV1 + o];
    pb[b * EV1 + o] = acc;
}

// ---------------- fused e3 + e4 tail ----------------
__global__ void k_e34(const float* __restrict__ e2out, const float* __restrict__ e3t,
                      const float* __restrict__ e3b, const float* __restrict__ e4w,
                      const float* __restrict__ e4b, float* __restrict__ out) {
    __shared__ float wt[EV2 * EV3];
    for (int idx = threadIdx.x; idx < EV2 * EV3; idx += 256) wt[idx] = e3t[idx];
    __syncthreads();
    int r = blockIdx.x * 256 + threadIdx.x;
    if (r >= ROWS) return;
    float h3[EV3];
#pragma unroll
    for (int o3 = 0; o3 < EV3; o3++) h3[o3] = e3b[o3];
    for (int k = 0; k < EV2; k++) {
        float v = e2out[(size_t)r * EV2 + k];
#pragma unroll
        for (int o3 = 0; o3 < EV3; o3++) h3[o3] += v * wt[k * EV3 + o3];
    }
    float acc = e4b[0];
#pragma unroll
    for (int o3 = 0; o3 < EV3; o3++) acc += fmaxf(h3[o3], 0.f) * e4w[o3];
    out[r] = fmaxf(acc, 0.f);
}

// ---------------- host launch ----------------
extern "C" void kernel_launch(void* const* d_in, const int* in_sizes, int n_in,
                              void* d_out, int out_size, void* d_ws, size_t ws_size,
                              hipStream_t stream) {
    const float* x    = (const float*)d_in[0];
    const float* w_ih = (const float*)d_in[1];
    const float* w_hh = (const float*)d_in[2];
    const float* b_ih = (const float*)d_in[3];
    const float* b_hh = (const float*)d_in[4];
    const float* q1_w = (const float*)d_in[5];
    const float* q1_b = (const float*)d_in[6];
    const float* q2_w = (const float*)d_in[7];
    const float* q2_b = (const float*)d_in[8];
    const float* e1_w = (const float*)d_in[9];
    const float* e1_b = (const float*)d_in[10];
    const float* e2_w = (const float*)d_in[11];
    const float* e2_b = (const float*)d_in[12];
    const float* e3_w = (const float*)d_in[13];
    const float* e3_b = (const float*)d_in[14];
    const float* e4_w = (const float*)d_in[15];
    const float* e4_b = (const float*)d_in[16];
    float* out = (float*)d_out;
    float* ws = (float*)d_ws;

    // workspace layout (float offsets)
    size_t off = 0;
    float* seq    = ws + off; off += (size_t)NN * BB * EE;          // 262,144
    size_t regionA = off; off += 17700000;
    // regionA phases:
    //  pre-LSTM : xg [0, 6.15M)
    //  pairs/q1 : pairs [0,8.13M) | q1out [8.13M,17.66M)   (xg dead after xgT)
    //  e1       : e1out [0,15.87M)                          (pairs,q1out dead)
    float* xg     = ws + regionA;                                   // 6,144,000
    float* pairs  = ws + regionA;                                   // 8,126,464
    float* q1out  = ws + regionA + 8130000;                         // 9,523,200
    float* e1out  = ws + regionA;                                   // 15,872,000
    float* xgT    = ws + off; off += (size_t)NN * G4 * BB;          // 6,144,000
    float* ht     = ws + off; off += 2 * BH;                        // 96,000 (ping-pong [2][1500][32])
    float* wih_t  = ws + off; off += (size_t)EE * G4;               // 1,536,000
    float* q1t    = ws + off; off += (size_t)QIN * Q1O;
    float* q1beff = ws + off; off += 1024;
    float* bsum   = ws + off; off += G4;
    float* q2t    = ws + off; off += (size_t)Q1O * QO;
    float* e1at   = ws + off; off += (size_t)HH * EV1;
    float* e1bt   = ws + off; off += (size_t)QO * EV1;
    float* e2t    = ws + off; off += (size_t)EV1 * EV2;
    float* e3t    = ws + off; off += 1024;
    float* pb     = ws + off; off += BB * EV1;
    float* q2out  = ws + off; off += (size_t)ROWS * QO;
    float* e2out  = ws + off; off += (size_t)ROWS * EV2;
    int*   iijj   = (int*)(ws + off); off += 1024;
    int*   bar    = (int*)(ws + off); off += 256;

    dim3 tb(32, 8);

    // init
    k_iijj<<<1, 512, 0, stream>>>(iijj);
    k_q1beff<<<3, 256, 0, stream>>>(q1_w, q1_b, q1beff);
    k_addb<<<24, 256, 0, stream>>>(b_ih, b_hh, bsum, G4);
    k_zero<<<376, 256, 0, stream>>>(ht, 2 * BH);
    k_zero<<<1, 256, 0, stream>>>((float*)bar, 64);

    // weight transforms
    k_transpose<<<dim3(8, 188), tb, 0, stream>>>(w_ih, wih_t, G4, EE, 0, EE);
    k_transpose<<<dim3(16, 19), tb, 0, stream>>>(q1_w, q1t, Q1O, QIN, 0, QIN);
    k_transpose<<<dim3(19, 10), tb, 0, stream>>>(q2_w, q2t, QO, Q1O, 0, Q1O);
    k_transpose<<<dim3(47, 32), tb, 0, stream>>>(e1_w, e1at, EV1, HH + QO, 0, HH);
    k_transpose<<<dim3(10, 32), tb, 0, stream>>>(e1_w, e1bt, EV1, HH + QO, HH, QO);
    k_transpose<<<dim3(32, 4), tb, 0, stream>>>(e2_w, e2t, EV2, EV1, 0, EV1);
    k_transpose<<<dim3(4, 1), tb, 0, stream>>>(e3_w, e3t, EV3, EV2, 0, EV2);

    // sort + x-side gates (xg = seq @ wih_t + bsum), then transpose to [n][j][b]
    k_sort<<<32, 256, 0, stream>>>(x, seq);
    k_gemm<<<dim3(94, 16), 256, 0, stream>>>(seq, wih_t, bsum, nullptr, xg, 1024, EE, G4, 0);
    k_xgt<<<dim3(188, 1, 32), tb, 0, stream>>>(xg, xgT);

    // LSTM: single persistent kernel, 32 steps with internal grid barrier
    k_lstm_persist<<<NBLK, 512, 0, stream>>>(w_hh, xgT, ht, bar);

    // evaluator plan-side bias (plan = ht buffer 0 after 32 steps)
    k_pb<<<dim3(4, BB), 256, 0, stream>>>(ht, e1at, e1_b, pb);

    // pair MLP
    k_pairs<<<7936, 256, 0, stream>>>(x, iijj, pairs);
    k_gemm<<<dim3(10, 248), 256, 0, stream>>>(pairs, q1t, q1beff, nullptr, q1out, ROWS, QIN, Q1O, 1);
    k_gemm<<<dim3(5, 248), 256, 0, stream>>>(q1out, q2t, q2_b, nullptr, q2out, ROWS, Q1O, QO, 1);
    k_gemm<<<dim3(16, 248), 256, 0, stream>>>(q2out, e1bt, nullptr, pb, e1out, ROWS, QO, EV1, 1);
    k_gemm<<<dim3(2, 248), 256, 0, stream>>>(e1out, e2t, e2_b, nullptr, e2out, ROWS, EV1, EV2, 1);
    k_e34<<<62, 256, 0, stream>>>(e2out, e3t, e3_b, e4_w, e4_b, out);
}

// Round 8
// 2537.545 us; speedup vs baseline: 1.7653x; 1.0059x over previous
//
#include <hip/hip_runtime.h>
#include <math.h>

// Problem dims
#define BB 32
#define NN 32
#define EE 256
#define HH 1500
#define G4 6000      // 4*HH
#define QIN 512
#define Q1O 600
#define QO 300
#define EV1 1000
#define EV2 100
#define EV3 10
#define PP 496       // N*(N-1)/2
#define ROWS (BB*PP) // 15872
#define BH (BB*HH)   // 48000

// persistent LSTM config
#define NBLK 250     // blocks (<=256 CUs, all resident)
#define JHB 6        // hidden units per block (250*6 = 1500)
#define TSL 24       // weight t-slots per thread (24*64 = 1536 >= 1500)
#define CKK 768      // k-chunk staged in LDS (2 chunks cover 1536)
#define HSTR 12      // hs row stride in floats (8 data + 4 pad; uniform 8/bank = b128 floor)

__device__ __forceinline__ float sigm(float x) { return 1.f / (1.f + expf(-x)); }

// ---------------- init helpers ----------------
__global__ void k_zero(float* a, int n) {
    int i = blockIdx.x * 256 + threadIdx.x;
    if (i < n) a[i] = 0.f;
}

__global__ void k_iijj(int* iijj) {
    int p = threadIdx.x;
    if (p >= PP) return;
    int i = 0, p0 = 0;
    while (p >= p0 + (NN - 1 - i)) { p0 += NN - 1 - i; i++; }
    iijj[p] = i;
    iijj[PP + p] = i + 1 + (p - p0);
}

// q1 effective bias: q1_b[o] + sum over odd k of q1_w[o][k]  (PE at pos 0)
__global__ void k_q1beff(const float* q1w, const float* q1b, float* beff) {
    int o = blockIdx.x * 256 + threadIdx.x;
    if (o >= Q1O) return;
    float a = q1b[o];
    for (int k = 1; k < QIN; k += 2) a += q1w[o * QIN + k];
    beff[o] = a;
}

__global__ void k_addb(const float* a, const float* b, float* c, int n) {
    int i = blockIdx.x * 256 + threadIdx.x;
    if (i < n) c[i] = a[i] + b[i];
}

// ---------------- transpose (sub-range of columns) ----------------
__global__ void k_transpose(const float* __restrict__ src, float* __restrict__ dst,
                            int R, int C, int c0, int csub) {
    __shared__ float tile[32][33];
    int cb = blockIdx.x * 32, rb = blockIdx.y * 32;
    for (int dy = threadIdx.y; dy < 32; dy += 8) {
        int r = rb + dy, c = cb + threadIdx.x;
        if (r < R && c < csub) tile[dy][threadIdx.x] = src[(size_t)r * C + c0 + c];
    }
    __syncthreads();
    for (int dy = threadIdx.y; dy < 32; dy += 8) {
        int c = cb + dy, r = rb + threadIdx.x;
        if (c < csub && r < R) dst[(size_t)c * R + r] = tile[threadIdx.x][dy];
    }
}

// ---------------- sort along parts axis ----------------
__global__ void k_sort(const float* __restrict__ x, float* __restrict__ seq) {
    int tid = blockIdx.x * 256 + threadIdx.x;
    if (tid >= BB * EE) return;
    int b = tid / EE, e = tid % EE;
    float v[NN];
    for (int n = 0; n < NN; n++) v[n] = x[(b * NN + n) * EE + e];
    for (int i = 1; i < NN; i++) {
        float key = v[i];
        int j = i - 1;
        while (j >= 0 && v[j] > key) { v[j + 1] = v[j]; j--; }
        v[j + 1] = key;
    }
    for (int n = 0; n < NN; n++) seq[(n * BB + b) * EE + e] = v[n];
}

// ---------------- transpose xg[(n*32+b)][j] -> xgT[n][j][b] ----------------
__global__ void k_xgt(const float* __restrict__ xg, float* __restrict__ xgT) {
    __shared__ float t[32][33];
    int n = blockIdx.z;
    int j0 = blockIdx.x * 32;
    for (int dy = threadIdx.y; dy < 32; dy += 8) {
        int j = j0 + threadIdx.x;
        if (j < G4) t[dy][threadIdx.x] = xg[(size_t)(n * 32 + dy) * G4 + j];
    }
    __syncthreads();
    for (int dy = threadIdx.y; dy < 32; dy += 8) {
        int j = j0 + dy;
        if (j < G4) xgT[(size_t)n * (G4 * BB) + (size_t)j * BB + threadIdx.x] = t[threadIdx.x][dy];
    }
}

// ---------------- pairs gather ----------------
__global__ void k_pairs(const float* __restrict__ x, const int* __restrict__ iijj,
                        float* __restrict__ pairs) {
    int idx = blockIdx.x * 256 + threadIdx.x; // quad index
    int r = idx >> 7;
    if (r >= ROWS) return;
    int q = idx & 127, k = q << 2;
    int b = r / PP, p = r - b * PP;
    int part = (k < EE) ? iijj[p] : iijj[PP + p];
    float4 v = *(const float4*)(x + (size_t)(b * NN + part) * EE + (k & (EE - 1)));
    *(float4*)(pairs + (size_t)r * QIN + k) = v;
}

// ---------------- tiled GEMM: C[M][N] = act(A[M][K] @ Bw[K][N] + bias + pb) ----------------
__global__ void k_gemm(const float* __restrict__ A, const float* __restrict__ Bw,
                       const float* __restrict__ bias, const float* __restrict__ pbm,
                       float* __restrict__ C, int M, int K, int N, int relu) {
    __shared__ __align__(16) float As[16][68];
    __shared__ __align__(16) float Bs[16][64];
    int tid = threadIdx.x;
    int m0 = blockIdx.y * 64, n0 = blockIdx.x * 64;
    int am = tid >> 2, ak4 = (tid & 3) << 2;
    int bk = tid >> 4, bn4 = (tid & 15) << 2;
    int tm = tid >> 4, tn = tid & 15;
    float acc[4][4] = {{0.f}};
    for (int k0 = 0; k0 < K; k0 += 16) {
        float4 av = {0.f, 0.f, 0.f, 0.f};
        if (k0 + ak4 < K) av = *(const float4*)(A + (size_t)(m0 + am) * K + k0 + ak4);
        float4 bv = {0.f, 0.f, 0.f, 0.f};
        if (k0 + bk < K && n0 + bn4 < N) bv = *(const float4*)(Bw + (size_t)(k0 + bk) * N + n0 + bn4);
        __syncthreads();
        As[ak4 + 0][am] = av.x; As[ak4 + 1][am] = av.y;
        As[ak4 + 2][am] = av.z; As[ak4 + 3][am] = av.w;
        *(float4*)&Bs[bk][bn4] = bv;
        __syncthreads();
#pragma unroll
        for (int kk = 0; kk < 16; kk++) {
            float4 a = *(const float4*)&As[kk][tm << 2];
            float4 b = *(const float4*)&Bs[kk][tn << 2];
            acc[0][0] += a.x * b.x; acc[0][1] += a.x * b.y; acc[0][2] += a.x * b.z; acc[0][3] += a.x * b.w;
            acc[1][0] += a.y * b.x; acc[1][1] += a.y * b.y; acc[1][2] += a.y * b.z; acc[1][3] += a.y * b.w;
            acc[2][0] += a.z * b.x; acc[2][1] += a.z * b.y; acc[2][2] += a.z * b.z; acc[2][3] += a.z * b.w;
            acc[3][0] += a.w * b.x; acc[3][1] += a.w * b.y; acc[3][2] += a.w * b.z; acc[3][3] += a.w * b.w;
        }
    }
    int col0 = n0 + (tn << 2);
    if (col0 >= N) return;
    float4 bb0 = {0.f, 0.f, 0.f, 0.f};
    if (bias) bb0 = *(const float4*)(bias + col0);
#pragma unroll
    for (int i = 0; i < 4; i++) {
        int row = m0 + (tm << 2) + i;
        float4 pv = {0.f, 0.f, 0.f, 0.f};
        if (pbm) pv = *(const float4*)(pbm + (size_t)(row / PP) * N + col0);
        float4 r;
        r.x = acc[i][0] + bb0.x + pv.x;
        r.y = acc[i][1] + bb0.y + pv.y;
        r.z = acc[i][2] + bb0.z + pv.z;
        r.w = acc[i][3] + bb0.w + pv.w;
        if (relu) {
            r.x = fmaxf(r.x, 0.f); r.y = fmaxf(r.y, 0.f);
            r.z = fmaxf(r.z, 0.f); r.w = fmaxf(r.w, 0.f);
        }
        *(float4*)(C + (size_t)row * N + col0) = r;
    }
}

// ---------------- persistent LSTM: all 32 steps in one kernel ----------------
// 250 blocks x 512 threads, all resident; weights register-resident (R6).
// Barrier history: R6 RMW-poll storm (~100us/step) -> R7 acquire-load poll
// still ~40us/step because EVERY acquire poll emits buffer_inv (L1+L2-remote
// invalidate), thrashing late blocks' caches across all XCDs. Now: RELEASE
// arrive (one wbl2), RELAXED polls (pure coherence-point loads, no cache
// maintenance), ONE acquire load after exit as the fence.
__global__ __attribute__((amdgpu_waves_per_eu(2))) __launch_bounds__(512)
void k_lstm_persist(const float* __restrict__ whh, const float* __restrict__ xgT,
                    float* __restrict__ ht, int* __restrict__ bar) {
    __shared__ __align__(16) float hs[CKK * HSTR];  // 36864 B
    __shared__ float red[24 * 8];                   // 768 B
    __shared__ float cs[JHB * BB];                  // 768 B
    const int tid = threadIdx.x;
    const int w = tid >> 6;   // wave = row-group of 3
    const int l = tid & 63;   // lane = k offset
    const int jh0 = blockIdx.x * JHB;

    // one-time weight load (coalesced: consecutive lanes -> consecutive k)
    float wreg[3][TSL];
#pragma unroll
    for (int i = 0; i < 3; i++) {
        int r = w * 3 + i;                 // r = g*JHB + u
        int g = r / JHB, u = r - g * JHB;
        const float* wr = whh + (size_t)(g * HH + jh0 + u) * HH;
#pragma unroll
        for (int t = 0; t < TSL; t++) {
            int k = (t << 6) + l;
            wreg[i][t] = (k < HH) ? wr[k] : 0.f;
        }
    }
    for (int idx = tid; idx < JHB * BB; idx += 512) cs[idx] = 0.f;
    __syncthreads();

    for (int n = 0; n < NN; n++) {
        const int pp = n & 1, np = pp ^ 1;
        const float* hsrc = ht + (size_t)pp * BH;
        float* hdst = ht + (size_t)np * BH;
#pragma unroll 1
        for (int o = 0; o < 4; o++) {
            const int b0 = o * 8;
            // prefetch gate-side xg early: latency hides under staging+FMA
            float xr[4];
            if (tid < JHB * 8) {
                int u = tid >> 3, bc = tid & 7;
                int jb = jh0 + u;
#pragma unroll
                for (int g = 0; g < 4; g++)
                    xr[g] = xgT[((size_t)n * G4 + (size_t)g * HH + jb) * BB + b0 + bc];
            }
            float acc[3][8];
#pragma unroll
            for (int i = 0; i < 3; i++)
#pragma unroll
                for (int b = 0; b < 8; b++) acc[i][b] = 0.f;
#pragma unroll
            for (int c = 0; c < 2; c++) {          // MUST be fully unrolled (wreg index)
                __syncthreads();  // hs reuse safe
                for (int fi = tid; fi < CKK * 2; fi += 512) {
                    int kk = fi >> 1, hf = fi & 1;
                    int k = c * CKK + kk;
                    float4 v = {0.f, 0.f, 0.f, 0.f};
                    if (k < HH) v = *(const float4*)(hsrc + (size_t)k * BB + b0 + (hf << 2));
                    *(float4*)&hs[kk * HSTR + (hf << 2)] = v;
                }
                __syncthreads();
#pragma unroll
                for (int t = 0; t < 12; t++) {
                    const float* hp = &hs[((t << 6) + l) * HSTR];
                    float4 ha = *(const float4*)hp;
                    float4 hb = *(const float4*)(hp + 4);
#pragma unroll
                    for (int i = 0; i < 3; i++) {
                        float wv = wreg[i][c * 12 + t];
                        acc[i][0] += wv * ha.x; acc[i][1] += wv * ha.y;
                        acc[i][2] += wv * ha.z; acc[i][3] += wv * ha.w;
                        acc[i][4] += wv * hb.x; acc[i][5] += wv * hb.y;
                        acc[i][6] += wv * hb.z; acc[i][7] += wv * hb.w;
                    }
                }
            }
            // butterfly reduce the 64-lane k-split
#pragma unroll
            for (int off = 32; off >= 1; off >>= 1)
#pragma unroll
                for (int i = 0; i < 3; i++)
#pragma unroll
                    for (int b = 0; b < 8; b++)
                        acc[i][b] += __shfl_xor(acc[i][b], off);
            if (l == 0) {
#pragma unroll
                for (int i = 0; i < 3; i++)
#pragma unroll
                    for (int b = 0; b < 8; b++)
                        red[(w * 3 + i) * 8 + b] = acc[i][b];
            }
            __syncthreads();
            // gate nonlinearity for this octet
            if (tid < JHB * 8) {
                int u = tid >> 3, bc = tid & 7;
                int jb = jh0 + u;
                float g4[4];
#pragma unroll
                for (int g = 0; g < 4; g++)
                    g4[g] = red[(g * JHB + u) * 8 + bc] + xr[g];
                float ci = cs[u * BB + b0 + bc];
                float cn = sigm(g4[1]) * ci + sigm(g4[0]) * tanhf(g4[2]);
                cs[u * BB + b0 + bc] = cn;
                hdst[(size_t)jb * BB + b0 + bc] = sigm(g4[3]) * tanhf(cn);
            }
        }
        // grid barrier: RELEASE arrive; RELAXED poll (no per-poll buffer_inv);
        // one ACQUIRE load after exit as the fence.
        __syncthreads();
        if (tid == 0) {
            __hip_atomic_fetch_add(bar, 1, __ATOMIC_RELEASE, __HIP_MEMORY_SCOPE_AGENT);
            const int target = NBLK * (n + 1);
            while (__hip_atomic_load(bar, __ATOMIC_RELAXED, __HIP_MEMORY_SCOPE_AGENT) < target)
                __builtin_amdgcn_s_sleep(2);
            (void)__hip_atomic_load(bar, __ATOMIC_ACQUIRE, __HIP_MEMORY_SCOPE_AGENT);
        }
        __syncthreads();
    }
}

// ---------------- plan-side e1 bias (plan = ht buffer 0, layout [k][32]) ----------------
__global__ void k_pb(const float* __restrict__ ht, const float* __restrict__ e1at,
                     const float* __restrict__ e1b, float* __restrict__ pb) {
    __shared__ float ps[HH];
    int b = blockIdx.y;
    for (int idx = threadIdx.x; idx < HH; idx += 256)
        ps[idx] = ht[(size_t)idx * BB + b];
    __syncthreads();
    int o = blockIdx.x * 256 + threadIdx.x;
    if (o >= EV1) return;
    float acc = e1b[o];
    for (int k = 0; k < HH; k++) acc += ps[k] * e1at[(size_t)k * EV1 + o];
    pb[b * EV1 + o] = acc;
}

// ---------------- fused e3 + e4 tail ----------------
__global__ void k_e34(const float* __restrict__ e2out, const float* __restrict__ e3t,
                      const float* __restrict__ e3b, const float* __restrict__ e4w,
                      const float* __restrict__ e4b, float* __restrict__ out) {
    __shared__ float wt[EV2 * EV3];
    for (int idx = threadIdx.x; idx < EV2 * EV3; idx += 256) wt[idx] = e3t[idx];
    __syncthreads();
    int r = blockIdx.x * 256 + threadIdx.x;
    if (r >= ROWS) return;
    float h3[EV3];
#pragma unroll
    for (int o3 = 0; o3 < EV3; o3++) h3[o3] = e3b[o3];
    for (int k = 0; k < EV2; k++) {
        float v = e2out[(size_t)r * EV2 + k];
#pragma unroll
        for (int o3 = 0; o3 < EV3; o3++) h3[o3] += v * wt[k * EV3 + o3];
    }
    float acc = e4b[0];
#pragma unroll
    for (int o3 = 0; o3 < EV3; o3++) acc += fmaxf(h3[o3], 0.f) * e4w[o3];
    out[r] = fmaxf(acc, 0.f);
}

// ---------------- host launch ----------------
extern "C" void kernel_launch(void* const* d_in, const int* in_sizes, int n_in,
                              void* d_out, int out_size, void* d_ws, size_t ws_size,
                              hipStream_t stream) {
    const float* x    = (const float*)d_in[0];
    const float* w_ih = (const float*)d_in[1];
    const float* w_hh = (const float*)d_in[2];
    const float* b_ih = (const float*)d_in[3];
    const float* b_hh = (const float*)d_in[4];
    const float* q1_w = (const float*)d_in[5];
    const float* q1_b = (const float*)d_in[6];
    const float* q2_w = (const float*)d_in[7];
    const float* q2_b = (const float*)d_in[8];
    const float* e1_w = (const float*)d_in[9];
    const float* e1_b = (const float*)d_in[10];
    const float* e2_w = (const float*)d_in[11];
    const float* e2_b = (const float*)d_in[12];
    const float* e3_w = (const float*)d_in[13];
    const float* e3_b = (const float*)d_in[14];
    const float* e4_w = (const float*)d_in[15];
    const float* e4_b = (const float*)d_in[16];
    float* out = (float*)d_out;
    float* ws = (float*)d_ws;

    // workspace layout (float offsets)
    size_t off = 0;
    float* seq    = ws + off; off += (size_t)NN * BB * EE;          // 262,144
    size_t regionA = off; off += 17700000;
    // regionA phases:
    //  pre-LSTM : xg [0, 6.15M)
    //  pairs/q1 : pairs [0,8.13M) | q1out [8.13M,17.66M)   (xg dead after xgT)
    //  e1       : e1out [0,15.87M)                          (pairs,q1out dead)
    float* xg     = ws + regionA;                                   // 6,144,000
    float* pairs  = ws + regionA;                                   // 8,126,464
    float* q1out  = ws + regionA + 8130000;                         // 9,523,200
    float* e1out  = ws + regionA;                                   // 15,872,000
    float* xgT    = ws + off; off += (size_t)NN * G4 * BB;          // 6,144,000
    float* ht     = ws + off; off += 2 * BH;                        // 96,000 (ping-pong [2][1500][32])
    float* wih_t  = ws + off; off += (size_t)EE * G4;               // 1,536,000
    float* q1t    = ws + off; off += (size_t)QIN * Q1O;
    float* q1beff = ws + off; off += 1024;
    float* bsum   = ws + off; off += G4;
    float* q2t    = ws + off; off += (size_t)Q1O * QO;
    float* e1at   = ws + off; off += (size_t)HH * EV1;
    float* e1bt   = ws + off; off += (size_t)QO * EV1;
    float* e2t    = ws + off; off += (size_t)EV1 * EV2;
    float* e3t    = ws + off; off += 1024;
    float* pb     = ws + off; off += BB * EV1;
    float* q2out  = ws + off; off += (size_t)ROWS * QO;
    float* e2out  = ws + off; off += (size_t)ROWS * EV2;
    int*   iijj   = (int*)(ws + off); off += 1024;
    int*   bar    = (int*)(ws + off); off += 256;

    dim3 tb(32, 8);

    // init
    k_iijj<<<1, 512, 0, stream>>>(iijj);
    k_q1beff<<<3, 256, 0, stream>>>(q1_w, q1_b, q1beff);
    k_addb<<<24, 256, 0, stream>>>(b_ih, b_hh, bsum, G4);
    k_zero<<<376, 256, 0, stream>>>(ht, 2 * BH);
    k_zero<<<1, 256, 0, stream>>>((float*)bar, 64);

    // weight transforms
    k_transpose<<<dim3(8, 188), tb, 0, stream>>>(w_ih, wih_t, G4, EE, 0, EE);
    k_transpose<<<dim3(16, 19), tb, 0, stream>>>(q1_w, q1t, Q1O, QIN, 0, QIN);
    k_transpose<<<dim3(19, 10), tb, 0, stream>>>(q2_w, q2t, QO, Q1O, 0, Q1O);
    k_transpose<<<dim3(47, 32), tb, 0, stream>>>(e1_w, e1at, EV1, HH + QO, 0, HH);
    k_transpose<<<dim3(10, 32), tb, 0, stream>>>(e1_w, e1bt, EV1, HH + QO, HH, QO);
    k_transpose<<<dim3(32, 4), tb, 0, stream>>>(e2_w, e2t, EV2, EV1, 0, EV1);
    k_transpose<<<dim3(4, 1), tb, 0, stream>>>(e3_w, e3t, EV3, EV2, 0, EV2);

    // sort + x-side gates (xg = seq @ wih_t + bsum), then transpose to [n][j][b]
    k_sort<<<32, 256, 0, stream>>>(x, seq);
    k_gemm<<<dim3(94, 16), 256, 0, stream>>>(seq, wih_t, bsum, nullptr, xg, 1024, EE, G4, 0);
    k_xgt<<<dim3(188, 1, 32), tb, 0, stream>>>(xg, xgT);

    // LSTM: single persistent kernel, 32 steps with internal grid barrier
    k_lstm_persist<<<NBLK, 512, 0, stream>>>(w_hh, xgT, ht, bar);

    // evaluator plan-side bias (plan = ht buffer 0 after 32 steps)
    k_pb<<<dim3(4, BB), 256, 0, stream>>>(ht, e1at, e1_b, pb);

    // pair MLP
    k_pairs<<<7936, 256, 0, stream>>>(x, iijj, pairs);
    k_gemm<<<dim3(10, 248), 256, 0, stream>>>(pairs, q1t, q1beff, nullptr, q1out, ROWS, QIN, Q1O, 1);
    k_gemm<<<dim3(5, 248), 256, 0, stream>>>(q1out, q2t, q2_b, nullptr, q2out, ROWS, Q1O, QO, 1);
    k_gemm<<<dim3(16, 248), 256, 0, stream>>>(q2out, e1bt, nullptr, pb, e1out, ROWS, QO, EV1, 1);
    k_gemm<<<dim3(2, 248), 256, 0, stream>>>(e1out, e2t, e2_b, nullptr, e2out, ROWS, EV1, EV2, 1);
    k_e34<<<62, 256, 0, stream>>>(e2out, e3t, e3_b, e4_w, e4_b, out);
}